// Round 1
// baseline (537.938 us; speedup 1.0000x reference)
//
#include <hip/hip_runtime.h>

typedef float f32x4 __attribute__((ext_vector_type(4)));
typedef __bf16 bf16x8 __attribute__((ext_vector_type(8)));

static __device__ __forceinline__ unsigned short f2bf(float f) {
    unsigned int u = __builtin_bit_cast(unsigned int, f);
    u += 0x7fffu + ((u >> 16) & 1u);
    return (unsigned short)(u >> 16);
}

// ---------------- QKV GEMM ----------------
// C[8192,3072] = x[8192,1024] @ w_qkv[1024,3072] + b_qkv
// Q,K -> [B,H,T,HD] bf16 ; V -> transposed [B,H,HD,T] bf16
#define BM 128
#define BN 128
#define BK 32
#define LDA 56   // LDS row stride (elems): 112B, 16B-aligned, 2-way bank cycle

__global__ __launch_bounds__(256)
void qkv_gemm(const float* __restrict__ A, const float* __restrict__ Bw,
              const float* __restrict__ bias,
              unsigned short* __restrict__ q_ws,
              unsigned short* __restrict__ k_ws,
              unsigned short* __restrict__ vT_ws)
{
    const int K = 1024, N = 3072;
    __shared__ unsigned short Al[BM * LDA];
    __shared__ unsigned short Bl[BN * LDA];
    const int tid = threadIdx.x;
    const int lane = tid & 63, wid = tid >> 6;
    const int l15 = lane & 15, lhi = lane >> 4;
    const int m0 = blockIdx.x * BM, n0 = blockIdx.y * BN;
    const int wm = (wid >> 1) * 64, wn = (wid & 1) * 64;

    f32x4 acc[4][4] = {};

    for (int k0 = 0; k0 < K; k0 += BK) {
        __syncthreads();
        // stage A tile 128x32 fp32 -> bf16
        #pragma unroll
        for (int i = 0; i < 4; i++) {
            int f = i * 256 + tid;
            int row = f >> 3, kq = (f & 7) << 2;
            float4 v = *(const float4*)(A + (m0 + row) * K + k0 + kq);
            ushort4 sv = make_ushort4(f2bf(v.x), f2bf(v.y), f2bf(v.z), f2bf(v.w));
            *(ushort4*)(Al + row * LDA + kq) = sv;
        }
        // stage B tile 32x128 fp32 -> bf16, transposed ([n][k])
        #pragma unroll
        for (int i = 0; i < 4; i++) {
            int f = i * 256 + tid;
            int krow = f >> 5, nq = (f & 31) << 2;
            float4 v = *(const float4*)(Bw + (k0 + krow) * N + n0 + nq);
            Bl[(nq + 0) * LDA + krow] = f2bf(v.x);
            Bl[(nq + 1) * LDA + krow] = f2bf(v.y);
            Bl[(nq + 2) * LDA + krow] = f2bf(v.z);
            Bl[(nq + 3) * LDA + krow] = f2bf(v.w);
        }
        __syncthreads();
        bf16x8 af[4], bfr[4];
        #pragma unroll
        for (int m = 0; m < 4; m++)
            af[m] = *(const bf16x8*)(Al + (wm + m * 16 + l15) * LDA + lhi * 8);
        #pragma unroll
        for (int n = 0; n < 4; n++)
            bfr[n] = *(const bf16x8*)(Bl + (wn + n * 16 + l15) * LDA + lhi * 8);
        #pragma unroll
        for (int m = 0; m < 4; m++)
            #pragma unroll
            for (int n = 0; n < 4; n++)
                acc[m][n] = __builtin_amdgcn_mfma_f32_16x16x32_bf16(af[m], bfr[n], acc[m][n], 0, 0, 0);
    }

    #pragma unroll
    for (int n = 0; n < 4; n++) {
        int col = n0 + wn + n * 16 + l15;
        float bv = bias[col];
        int which = col >> 10;          // 0=Q 1=K 2=V
        int d = col & 1023;
        int h = d >> 6, hd = d & 63;
        #pragma unroll
        for (int m = 0; m < 4; m++) {
            #pragma unroll
            for (int j = 0; j < 4; j++) {
                int row = m0 + wm + m * 16 + lhi * 4 + j;
                int b = row >> 11, t = row & 2047;
                unsigned short bf = f2bf(acc[m][n][j] + bv);
                int bh = b * 16 + h;
                if (which == 0)      q_ws[(bh * 2048 + t) * 64 + hd] = bf;
                else if (which == 1) k_ws[(bh * 2048 + t) * 64 + hd] = bf;
                else                 vT_ws[(bh * 64 + hd) * 2048 + t] = bf;
            }
        }
    }
}

// ---------------- Flash attention (causal) ----------------
#define QB 128
#define KVB 64
#define LK 72   // LDS row stride: 144B, 16B-aligned

__global__ __launch_bounds__(256)
void attn_fwd(const unsigned short* __restrict__ q_ws,
              const unsigned short* __restrict__ k_ws,
              const unsigned short* __restrict__ vT_ws,
              unsigned short* __restrict__ attn_ws)
{
    __shared__ unsigned short Kl[KVB * LK];     // K tile [k][d]
    __shared__ unsigned short Vl[64 * LK];      // V^T tile [d][k]
    __shared__ unsigned short Pl[4][32 * LK];   // per-wave P

    const int bh = blockIdx.x;      // b*16+h
    const int qb = blockIdx.y;
    const int b = bh >> 4, h = bh & 15;
    const int tid = threadIdx.x;
    const int lane = tid & 63, wid = tid >> 6;
    const int l15 = lane & 15, lhi = lane >> 4;
    const int q0 = qb * QB;
    const int qrow = q0 + wid * 32;
    const int tbase = bh * 2048;

    // hoist Q fragments into registers (read once from global)
    bf16x8 qf[2][2];
    #pragma unroll
    for (int m = 0; m < 2; m++)
        #pragma unroll
        for (int ks = 0; ks < 2; ks++)
            qf[m][ks] = *(const bf16x8*)(q_ws + (tbase + qrow + m * 16 + l15) * 64 + ks * 32 + lhi * 8);

    f32x4 o[2][4] = {};
    float mst[2][4], lst[2][4];
    #pragma unroll
    for (int m = 0; m < 2; m++)
        #pragma unroll
        for (int j = 0; j < 4; j++) { mst[m][j] = -__builtin_inff(); lst[m][j] = 0.f; }

    const int nkv = (q0 + QB) / KVB;
    for (int kb = 0; kb < nkv; kb++) {
        const int k0 = kb * KVB;
        __syncthreads();
        #pragma unroll
        for (int i = 0; i < 2; i++) {
            int f = i * 256 + tid;
            int row = f >> 3, dq = (f & 7) << 3;
            *(uint4*)(Kl + row * LK + dq) = *(const uint4*)(k_ws + (tbase + k0 + row) * 64 + dq);
            *(uint4*)(Vl + row * LK + dq) = *(const uint4*)(vT_ws + (bh * 64 + row) * 2048 + k0 + dq);
        }
        __syncthreads();
        if (k0 <= qrow + 31) {   // wave-uniform: skip fully-masked kv blocks
            // S = Q K^T
            f32x4 s[2][4] = {};
            #pragma unroll
            for (int ks = 0; ks < 2; ks++) {
                bf16x8 kf[4];
                #pragma unroll
                for (int n = 0; n < 4; n++)
                    kf[n] = *(const bf16x8*)(Kl + (n * 16 + l15) * LK + ks * 32 + lhi * 8);
                #pragma unroll
                for (int m = 0; m < 2; m++)
                    #pragma unroll
                    for (int n = 0; n < 4; n++)
                        s[m][n] = __builtin_amdgcn_mfma_f32_16x16x32_bf16(qf[m][ks], kf[n], s[m][n], 0, 0, 0);
            }
            // scale + causal mask + online softmax (wave-parallel, 16-lane groups)
            float al[2][4];
            #pragma unroll
            for (int m = 0; m < 2; m++) {
                #pragma unroll
                for (int j = 0; j < 4; j++) {
                    int grow = qrow + m * 16 + lhi * 4 + j;
                    #pragma unroll
                    for (int n = 0; n < 4; n++) {
                        int gcol = k0 + n * 16 + l15;
                        float v = s[m][n][j] * 0.125f;
                        s[m][n][j] = (gcol <= grow) ? v : -__builtin_inff();
                    }
                    float mx = fmaxf(fmaxf(s[m][0][j], s[m][1][j]), fmaxf(s[m][2][j], s[m][3][j]));
                    mx = fmaxf(mx, __shfl_xor(mx, 1));
                    mx = fmaxf(mx, __shfl_xor(mx, 2));
                    mx = fmaxf(mx, __shfl_xor(mx, 4));
                    mx = fmaxf(mx, __shfl_xor(mx, 8));
                    float mnew = fmaxf(mst[m][j], mx);
                    float alpha = expf(mst[m][j] - mnew);
                    float rs = 0.f;
                    #pragma unroll
                    for (int n = 0; n < 4; n++) {
                        float p = expf(s[m][n][j] - mnew);
                        s[m][n][j] = p;
                        rs += p;
                    }
                    rs += __shfl_xor(rs, 1);
                    rs += __shfl_xor(rs, 2);
                    rs += __shfl_xor(rs, 4);
                    rs += __shfl_xor(rs, 8);
                    lst[m][j] = lst[m][j] * alpha + rs;
                    mst[m][j] = mnew;
                    al[m][j] = alpha;
                }
            }
            // rescale O
            #pragma unroll
            for (int m = 0; m < 2; m++)
                #pragma unroll
                for (int nd = 0; nd < 4; nd++)
                    #pragma unroll
                    for (int j = 0; j < 4; j++)
                        o[m][nd][j] *= al[m][j];
            // P -> LDS (re-layout for PV A operand)
            #pragma unroll
            for (int m = 0; m < 2; m++)
                #pragma unroll
                for (int n = 0; n < 4; n++)
                    #pragma unroll
                    for (int j = 0; j < 4; j++)
                        Pl[wid][(m * 16 + lhi * 4 + j) * LK + n * 16 + l15] = f2bf(s[m][n][j]);
            // O += P @ V
            #pragma unroll
            for (int ks = 0; ks < 2; ks++) {
                bf16x8 pf[2], vf[4];
                #pragma unroll
                for (int m = 0; m < 2; m++)
                    pf[m] = *(const bf16x8*)(&Pl[wid][(m * 16 + l15) * LK + ks * 32 + lhi * 8]);
                #pragma unroll
                for (int nd = 0; nd < 4; nd++)
                    vf[nd] = *(const bf16x8*)(Vl + (nd * 16 + l15) * LK + ks * 32 + lhi * 8);
                #pragma unroll
                for (int m = 0; m < 2; m++)
                    #pragma unroll
                    for (int nd = 0; nd < 4; nd++)
                        o[m][nd] = __builtin_amdgcn_mfma_f32_16x16x32_bf16(pf[m], vf[nd], o[m][nd], 0, 0, 0);
            }
        }
    }
    // epilogue: O/l -> attn_ws [B,T,H,HD] bf16
    #pragma unroll
    for (int m = 0; m < 2; m++) {
        #pragma unroll
        for (int j = 0; j < 4; j++) {
            float inv = 1.0f / lst[m][j];
            int t = qrow + m * 16 + lhi * 4 + j;
            #pragma unroll
            for (int nd = 0; nd < 4; nd++) {
                int d = nd * 16 + l15;
                attn_ws[((b * 2048 + t) * 16 + h) * 64 + d] = f2bf(o[m][nd][j] * inv);
            }
        }
    }
}

// ---------------- Output projection GEMM ----------------
// out[8192,1024] = attn[8192,1024](bf16) @ w_proj[1024,1024] + b_proj
__global__ __launch_bounds__(256)
void proj_gemm(const unsigned short* __restrict__ A, const float* __restrict__ Bw,
               const float* __restrict__ bias, float* __restrict__ out)
{
    const int K = 1024, N = 1024;
    __shared__ unsigned short Al[BM * LDA];
    __shared__ unsigned short Bl[BN * LDA];
    const int tid = threadIdx.x;
    const int lane = tid & 63, wid = tid >> 6;
    const int l15 = lane & 15, lhi = lane >> 4;
    const int m0 = blockIdx.x * BM, n0 = blockIdx.y * BN;
    const int wm = (wid >> 1) * 64, wn = (wid & 1) * 64;

    f32x4 acc[4][4] = {};

    for (int k0 = 0; k0 < K; k0 += BK) {
        __syncthreads();
        // stage A (already bf16), 16B per thread
        #pragma unroll
        for (int i = 0; i < 2; i++) {
            int f = i * 256 + tid;
            int row = f >> 2, kq = (f & 3) << 3;
            *(uint4*)(Al + row * LDA + kq) = *(const uint4*)(A + (m0 + row) * K + k0 + kq);
        }
        // stage B fp32 -> bf16 transposed
        #pragma unroll
        for (int i = 0; i < 4; i++) {
            int f = i * 256 + tid;
            int krow = f >> 5, nq = (f & 31) << 2;
            float4 v = *(const float4*)(Bw + (k0 + krow) * N + n0 + nq);
            Bl[(nq + 0) * LDA + krow] = f2bf(v.x);
            Bl[(nq + 1) * LDA + krow] = f2bf(v.y);
            Bl[(nq + 2) * LDA + krow] = f2bf(v.z);
            Bl[(nq + 3) * LDA + krow] = f2bf(v.w);
        }
        __syncthreads();
        bf16x8 af[4], bfr[4];
        #pragma unroll
        for (int m = 0; m < 4; m++)
            af[m] = *(const bf16x8*)(Al + (wm + m * 16 + l15) * LDA + lhi * 8);
        #pragma unroll
        for (int n = 0; n < 4; n++)
            bfr[n] = *(const bf16x8*)(Bl + (wn + n * 16 + l15) * LDA + lhi * 8);
        #pragma unroll
        for (int m = 0; m < 4; m++)
            #pragma unroll
            for (int n = 0; n < 4; n++)
                acc[m][n] = __builtin_amdgcn_mfma_f32_16x16x32_bf16(af[m], bfr[n], acc[m][n], 0, 0, 0);
    }

    #pragma unroll
    for (int n = 0; n < 4; n++) {
        int col = n0 + wn + n * 16 + l15;
        float bv = bias[col];
        #pragma unroll
        for (int m = 0; m < 4; m++)
            #pragma unroll
            for (int j = 0; j < 4; j++) {
                int row = m0 + wm + m * 16 + lhi * 4 + j;
                out[row * N + col] = acc[m][n][j] + bv;
            }
    }
}

extern "C" void kernel_launch(void* const* d_in, const int* in_sizes, int n_in,
                              void* d_out, int out_size, void* d_ws, size_t ws_size,
                              hipStream_t stream)
{
    const float* x      = (const float*)d_in[0];
    const float* w_qkv  = (const float*)d_in[1];
    const float* b_qkv  = (const float*)d_in[2];
    const float* w_proj = (const float*)d_in[3];
    const float* b_proj = (const float*)d_in[4];
    float* out = (float*)d_out;

    const size_t SEG = (size_t)8 * 1024 * 1024;   // 8,388,608 elems = B*H*T*HD
    unsigned short* q_ws    = (unsigned short*)d_ws;
    unsigned short* k_ws    = q_ws + SEG;
    unsigned short* vT_ws   = k_ws + SEG;
    unsigned short* attn_ws = vT_ws + SEG;

    qkv_gemm<<<dim3(64, 24), 256, 0, stream>>>(x, w_qkv, b_qkv, q_ws, k_ws, vT_ws);
    attn_fwd<<<dim3(64, 16), 256, 0, stream>>>(q_ws, k_ws, vT_ws, attn_ws);
    proj_gemm<<<dim3(64, 8), 256, 0, stream>>>(attn_ws, w_proj, b_proj, out);
}

// Round 2
// 333.351 us; speedup vs baseline: 1.6137x; 1.6137x over previous
//
#include <hip/hip_runtime.h>

typedef float f32x4 __attribute__((ext_vector_type(4)));
typedef __bf16 bf16x8 __attribute__((ext_vector_type(8)));

static __device__ __forceinline__ unsigned short f2bf(float f) {
    unsigned int u = __builtin_bit_cast(unsigned int, f);
    u += 0x7fffu + ((u >> 16) & 1u);
    return (unsigned short)(u >> 16);
}

typedef const __attribute__((address_space(1))) unsigned int gu32;
typedef __attribute__((address_space(3))) unsigned int lu32;
static __device__ __forceinline__ void gload_lds16(const unsigned short* g, unsigned short* l) {
    // stages 64 lanes x 16B: LDS dest = wave-uniform l + lane*16 (linear), global src per-lane
    __builtin_amdgcn_global_load_lds((gu32*)g, (lu32*)l, 16, 0, 0);
}

// ---------------- fp32 -> bf16 elementwise convert ----------------
__global__ __launch_bounds__(256)
void cvt_bf16(const float* __restrict__ in, unsigned short* __restrict__ out) {
    int i = blockIdx.x * 256 + threadIdx.x;          // 8 elems/thread
    const float4* p = (const float4*)in + (size_t)i * 2;
    float4 a = p[0], b = p[1];
    union { unsigned short s[8]; uint4 v; } u;
    u.s[0] = f2bf(a.x); u.s[1] = f2bf(a.y); u.s[2] = f2bf(a.z); u.s[3] = f2bf(a.w);
    u.s[4] = f2bf(b.x); u.s[5] = f2bf(b.y); u.s[6] = f2bf(b.z); u.s[7] = f2bf(b.w);
    ((uint4*)out)[i] = u.v;
}

// ---------------- weight transpose+convert: w[K][N] fp32 -> wT[N][K] bf16 ----------------
__global__ __launch_bounds__(256)
void transpose_w(const float* __restrict__ w, unsigned short* __restrict__ wT,
                 int K, int N) {
    __shared__ unsigned short Lt[64][65];
    const int k0 = blockIdx.x * 64, n0 = blockIdx.y * 64;
    const int t = threadIdx.x;
    const int r = t >> 4, c4 = (t & 15) * 4;
    #pragma unroll
    for (int i = 0; i < 4; i++) {
        int rr = r + i * 16;
        float4 v = *(const float4*)(w + (k0 + rr) * N + n0 + c4);
        Lt[rr][c4 + 0] = f2bf(v.x); Lt[rr][c4 + 1] = f2bf(v.y);
        Lt[rr][c4 + 2] = f2bf(v.z); Lt[rr][c4 + 3] = f2bf(v.w);
    }
    __syncthreads();
    const int rn = t >> 3, ks = (t & 7) * 8;
    #pragma unroll
    for (int i = 0; i < 2; i++) {
        int rr = rn + i * 32;
        unsigned short tmp[8];
        #pragma unroll
        for (int j = 0; j < 8; j++) tmp[j] = Lt[ks + j][rr];
        *(uint4*)(wT + (n0 + rr) * K + k0 + ks) = *(const uint4*)tmp;
    }
}

// ---------------- QKV GEMM (m97 structure) ----------------
// C[8192,3072] = x_bf[8192,1024] @ wqkvT[3072,1024]^T + b_qkv
// epilogue scatters Q,K -> [B,H,T,HD] bf16 ; V -> [B,H,HD,T] bf16
__global__ __launch_bounds__(256)
void qkv_gemm2(const unsigned short* __restrict__ A,
               const unsigned short* __restrict__ Bt,
               const float* __restrict__ bias,
               unsigned short* __restrict__ q_ws,
               unsigned short* __restrict__ k_ws,
               unsigned short* __restrict__ vT_ws)
{
    const int K = 1024;
    __shared__ unsigned short Al[128 * 32];
    __shared__ unsigned short Bl[128 * 32];
    const int tid = threadIdx.x;
    const int lane = tid & 63, w = tid >> 6;
    const int l15 = lane & 15, lhi = lane >> 4;
    const int m0 = blockIdx.x * 128, n0 = blockIdx.y * 128;
    const int wm = (w >> 1) * 64, wn = (w & 1) * 64;

    // staging: wave w, call c stages 16 rows (w*32 + c*16 ...) of the 128-row tile
    const int srow = w * 32 + (lane >> 2);
    const int sslot = lane & 3;
    const unsigned short* ga = A + (size_t)(m0 + srow) * K + sslot * 8;
    const unsigned short* gb = Bt + (size_t)(n0 + srow) * K + sslot * 8;
    unsigned short* la = Al + w * 32 * 32;   // wave-uniform LDS base
    unsigned short* lb = Bl + w * 32 * 32;

    f32x4 acc[4][4] = {};

    for (int k0 = 0; k0 < K; k0 += 32) {
        __syncthreads();
        gload_lds16(ga + k0,          la);
        gload_lds16(ga + k0 + 16 * K, la + 16 * 32);
        gload_lds16(gb + k0,          lb);
        gload_lds16(gb + k0 + 16 * K, lb + 16 * 32);
        __syncthreads();
        bf16x8 af[4], bfr[4];
        #pragma unroll
        for (int m = 0; m < 4; m++)
            af[m] = *(const bf16x8*)(Al + (wm + m * 16 + l15) * 32 + lhi * 8);
        #pragma unroll
        for (int n = 0; n < 4; n++)
            bfr[n] = *(const bf16x8*)(Bl + (wn + n * 16 + l15) * 32 + lhi * 8);
        #pragma unroll
        for (int m = 0; m < 4; m++)
            #pragma unroll
            for (int n = 0; n < 4; n++)
                acc[m][n] = __builtin_amdgcn_mfma_f32_16x16x32_bf16(af[m], bfr[n], acc[m][n], 0, 0, 0);
    }

    #pragma unroll
    for (int n = 0; n < 4; n++) {
        int col = n0 + wn + n * 16 + l15;
        float bv = bias[col];
        int which = col >> 10;          // 0=Q 1=K 2=V
        int d = col & 1023;
        int h = d >> 6, hd = d & 63;
        #pragma unroll
        for (int m = 0; m < 4; m++) {
            #pragma unroll
            for (int j = 0; j < 4; j++) {
                int row = m0 + wm + m * 16 + lhi * 4 + j;
                int b = row >> 11, t = row & 2047;
                unsigned short bf = f2bf(acc[m][n][j] + bv);
                int bh = b * 16 + h;
                if (which == 0)      q_ws[(bh * 2048 + t) * 64 + hd] = bf;
                else if (which == 1) k_ws[(bh * 2048 + t) * 64 + hd] = bf;
                else                 vT_ws[(bh * 64 + hd) * 2048 + t] = bf;
            }
        }
    }
}

// ---------------- Flash attention (causal) ----------------
#define QB 128
#define KVB 64
#define LK 72   // LDS row stride: 144B, 16B-aligned

__global__ __launch_bounds__(256)
void attn_fwd(const unsigned short* __restrict__ q_ws,
              const unsigned short* __restrict__ k_ws,
              const unsigned short* __restrict__ vT_ws,
              unsigned short* __restrict__ attn_ws)
{
    __shared__ unsigned short Kl[KVB * LK];     // K tile [k][d]
    __shared__ unsigned short Vl[64 * LK];      // V^T tile [d][k]
    __shared__ unsigned short Pl[4][32 * LK];   // per-wave P

    const int bh = blockIdx.x;      // b*16+h
    const int qb = blockIdx.y;
    const int b = bh >> 4, h = bh & 15;
    const int tid = threadIdx.x;
    const int lane = tid & 63, wid = tid >> 6;
    const int l15 = lane & 15, lhi = lane >> 4;
    const int q0 = qb * QB;
    const int qrow = q0 + wid * 32;
    const int tbase = bh * 2048;

    bf16x8 qf[2][2];
    #pragma unroll
    for (int m = 0; m < 2; m++)
        #pragma unroll
        for (int ks = 0; ks < 2; ks++)
            qf[m][ks] = *(const bf16x8*)(q_ws + (tbase + qrow + m * 16 + l15) * 64 + ks * 32 + lhi * 8);

    f32x4 o[2][4] = {};
    float mst[2][4], lst[2][4];
    #pragma unroll
    for (int m = 0; m < 2; m++)
        #pragma unroll
        for (int j = 0; j < 4; j++) { mst[m][j] = -__builtin_inff(); lst[m][j] = 0.f; }

    const int nkv = (q0 + QB) / KVB;
    for (int kb = 0; kb < nkv; kb++) {
        const int k0 = kb * KVB;
        __syncthreads();
        #pragma unroll
        for (int i = 0; i < 2; i++) {
            int f = i * 256 + tid;
            int row = f >> 3, dq = (f & 7) << 3;
            *(uint4*)(Kl + row * LK + dq) = *(const uint4*)(k_ws + (tbase + k0 + row) * 64 + dq);
            *(uint4*)(Vl + row * LK + dq) = *(const uint4*)(vT_ws + (bh * 64 + row) * 2048 + k0 + dq);
        }
        __syncthreads();
        if (k0 <= qrow + 31) {
            f32x4 s[2][4] = {};
            #pragma unroll
            for (int ks = 0; ks < 2; ks++) {
                bf16x8 kf[4];
                #pragma unroll
                for (int n = 0; n < 4; n++)
                    kf[n] = *(const bf16x8*)(Kl + (n * 16 + l15) * LK + ks * 32 + lhi * 8);
                #pragma unroll
                for (int m = 0; m < 2; m++)
                    #pragma unroll
                    for (int n = 0; n < 4; n++)
                        s[m][n] = __builtin_amdgcn_mfma_f32_16x16x32_bf16(qf[m][ks], kf[n], s[m][n], 0, 0, 0);
            }
            float al[2][4];
            #pragma unroll
            for (int m = 0; m < 2; m++) {
                #pragma unroll
                for (int j = 0; j < 4; j++) {
                    int grow = qrow + m * 16 + lhi * 4 + j;
                    #pragma unroll
                    for (int n = 0; n < 4; n++) {
                        int gcol = k0 + n * 16 + l15;
                        float v = s[m][n][j] * 0.125f;
                        s[m][n][j] = (gcol <= grow) ? v : -__builtin_inff();
                    }
                    float mx = fmaxf(fmaxf(s[m][0][j], s[m][1][j]), fmaxf(s[m][2][j], s[m][3][j]));
                    mx = fmaxf(mx, __shfl_xor(mx, 1));
                    mx = fmaxf(mx, __shfl_xor(mx, 2));
                    mx = fmaxf(mx, __shfl_xor(mx, 4));
                    mx = fmaxf(mx, __shfl_xor(mx, 8));
                    float mnew = fmaxf(mst[m][j], mx);
                    float alpha = expf(mst[m][j] - mnew);
                    float rs = 0.f;
                    #pragma unroll
                    for (int n = 0; n < 4; n++) {
                        float p = expf(s[m][n][j] - mnew);
                        s[m][n][j] = p;
                        rs += p;
                    }
                    rs += __shfl_xor(rs, 1);
                    rs += __shfl_xor(rs, 2);
                    rs += __shfl_xor(rs, 4);
                    rs += __shfl_xor(rs, 8);
                    lst[m][j] = lst[m][j] * alpha + rs;
                    mst[m][j] = mnew;
                    al[m][j] = alpha;
                }
            }
            #pragma unroll
            for (int m = 0; m < 2; m++)
                #pragma unroll
                for (int nd = 0; nd < 4; nd++)
                    #pragma unroll
                    for (int j = 0; j < 4; j++)
                        o[m][nd][j] *= al[m][j];
            #pragma unroll
            for (int m = 0; m < 2; m++)
                #pragma unroll
                for (int n = 0; n < 4; n++)
                    #pragma unroll
                    for (int j = 0; j < 4; j++)
                        Pl[wid][(m * 16 + lhi * 4 + j) * LK + n * 16 + l15] = f2bf(s[m][n][j]);
            #pragma unroll
            for (int ks = 0; ks < 2; ks++) {
                bf16x8 pf[2], vf[4];
                #pragma unroll
                for (int m = 0; m < 2; m++)
                    pf[m] = *(const bf16x8*)(&Pl[wid][(m * 16 + l15) * LK + ks * 32 + lhi * 8]);
                #pragma unroll
                for (int nd = 0; nd < 4; nd++)
                    vf[nd] = *(const bf16x8*)(Vl + (nd * 16 + l15) * LK + ks * 32 + lhi * 8);
                #pragma unroll
                for (int m = 0; m < 2; m++)
                    #pragma unroll
                    for (int nd = 0; nd < 4; nd++)
                        o[m][nd] = __builtin_amdgcn_mfma_f32_16x16x32_bf16(pf[m], vf[nd], o[m][nd], 0, 0, 0);
            }
        }
    }
    #pragma unroll
    for (int m = 0; m < 2; m++) {
        #pragma unroll
        for (int j = 0; j < 4; j++) {
            float inv = 1.0f / lst[m][j];
            int t = qrow + m * 16 + lhi * 4 + j;
            #pragma unroll
            for (int nd = 0; nd < 4; nd++) {
                int d = nd * 16 + l15;
                attn_ws[((b * 2048 + t) * 16 + h) * 64 + d] = f2bf(o[m][nd][j] * inv);
            }
        }
    }
}

// ---------------- Output projection GEMM (m97 structure) ----------------
// out[8192,1024] = attn[8192,1024](bf16) @ wprojT[1024,1024]^T + b_proj
__global__ __launch_bounds__(256)
void proj_gemm2(const unsigned short* __restrict__ A,
                const unsigned short* __restrict__ Bt,
                const float* __restrict__ bias, float* __restrict__ out)
{
    const int K = 1024, N = 1024;
    __shared__ unsigned short Al[128 * 32];
    __shared__ unsigned short Bl[128 * 32];
    const int tid = threadIdx.x;
    const int lane = tid & 63, w = tid >> 6;
    const int l15 = lane & 15, lhi = lane >> 4;
    const int m0 = blockIdx.x * 128, n0 = blockIdx.y * 128;
    const int wm = (w >> 1) * 64, wn = (w & 1) * 64;

    const int srow = w * 32 + (lane >> 2);
    const int sslot = lane & 3;
    const unsigned short* ga = A + (size_t)(m0 + srow) * K + sslot * 8;
    const unsigned short* gb = Bt + (size_t)(n0 + srow) * K + sslot * 8;
    unsigned short* la = Al + w * 32 * 32;
    unsigned short* lb = Bl + w * 32 * 32;

    f32x4 acc[4][4] = {};

    for (int k0 = 0; k0 < K; k0 += 32) {
        __syncthreads();
        gload_lds16(ga + k0,          la);
        gload_lds16(ga + k0 + 16 * K, la + 16 * 32);
        gload_lds16(gb + k0,          lb);
        gload_lds16(gb + k0 + 16 * K, lb + 16 * 32);
        __syncthreads();
        bf16x8 af[4], bfr[4];
        #pragma unroll
        for (int m = 0; m < 4; m++)
            af[m] = *(const bf16x8*)(Al + (wm + m * 16 + l15) * 32 + lhi * 8);
        #pragma unroll
        for (int n = 0; n < 4; n++)
            bfr[n] = *(const bf16x8*)(Bl + (wn + n * 16 + l15) * 32 + lhi * 8);
        #pragma unroll
        for (int m = 0; m < 4; m++)
            #pragma unroll
            for (int n = 0; n < 4; n++)
                acc[m][n] = __builtin_amdgcn_mfma_f32_16x16x32_bf16(af[m], bfr[n], acc[m][n], 0, 0, 0);
    }

    #pragma unroll
    for (int n = 0; n < 4; n++) {
        int col = n0 + wn + n * 16 + l15;
        float bv = bias[col];
        #pragma unroll
        for (int m = 0; m < 4; m++)
            #pragma unroll
            for (int j = 0; j < 4; j++) {
                int row = m0 + wm + m * 16 + lhi * 4 + j;
                out[row * N + col] = acc[m][n][j] + bv;
            }
    }
}

extern "C" void kernel_launch(void* const* d_in, const int* in_sizes, int n_in,
                              void* d_out, int out_size, void* d_ws, size_t ws_size,
                              hipStream_t stream)
{
    const float* x      = (const float*)d_in[0];
    const float* w_qkv  = (const float*)d_in[1];
    const float* b_qkv  = (const float*)d_in[2];
    const float* w_proj = (const float*)d_in[3];
    const float* b_proj = (const float*)d_in[4];
    float* out = (float*)d_out;

    // d_ws: 4 x 16MB segments (known-safe 64MB)
    const size_t SEG = (size_t)8 * 1024 * 1024;
    unsigned short* q_ws    = (unsigned short*)d_ws;
    unsigned short* k_ws    = q_ws + SEG;
    unsigned short* vT_ws   = k_ws + SEG;
    unsigned short* attn_ws = vT_ws + SEG;

    // d_out (32MB) doubles as scratch for bf16 operands; all dead before proj writes
    unsigned short* x_bf   = (unsigned short*)d_out;          // 16MB  [0,16M)
    unsigned short* wqkvT  = x_bf + SEG;                      // 6MB   [16M,22M)
    unsigned short* wprojT = q_ws;                            // reuse q (dead after attn)

    cvt_bf16<<<4096, 256, 0, stream>>>(x, x_bf);
    transpose_w<<<dim3(16, 48), 256, 0, stream>>>(w_qkv, wqkvT, 1024, 3072);
    qkv_gemm2<<<dim3(64, 24), 256, 0, stream>>>(x_bf, wqkvT, b_qkv, q_ws, k_ws, vT_ws);
    attn_fwd<<<dim3(64, 16), 256, 0, stream>>>(q_ws, k_ws, vT_ws, attn_ws);
    transpose_w<<<dim3(16, 16), 256, 0, stream>>>(w_proj, wprojT, 1024, 1024);
    proj_gemm2<<<dim3(64, 8), 256, 0, stream>>>(attn_ws, wprojT, b_proj, out);
}

// Round 3
// 253.531 us; speedup vs baseline: 2.1218x; 1.3148x over previous
//
#include <hip/hip_runtime.h>

typedef float f32x4 __attribute__((ext_vector_type(4)));
typedef __bf16 bf16x8 __attribute__((ext_vector_type(8)));

static __device__ __forceinline__ unsigned short f2bf(float f) {
    unsigned int u = __builtin_bit_cast(unsigned int, f);
    u += 0x7fffu + ((u >> 16) & 1u);
    return (unsigned short)(u >> 16);
}
static __device__ __forceinline__ unsigned short bfc(float f) {
    return __builtin_bit_cast(unsigned short, (__bf16)f);
}

#define QSC 0.18033688011112042f   // log2(e)/sqrt(HD) folded into Q

typedef const __attribute__((address_space(1))) unsigned int gu32;
typedef __attribute__((address_space(3))) unsigned int lu32;
static __device__ __forceinline__ void gload_lds16(const unsigned short* g, unsigned short* l) {
    __builtin_amdgcn_global_load_lds((gu32*)g, (lu32*)l, 16, 0, 0);
}

// ---------------- fp32 -> bf16 elementwise convert ----------------
__global__ __launch_bounds__(256)
void cvt_bf16(const float* __restrict__ in, unsigned short* __restrict__ out) {
    int i = blockIdx.x * 256 + threadIdx.x;
    const float4* p = (const float4*)in + (size_t)i * 2;
    float4 a = p[0], b = p[1];
    union { unsigned short s[8]; uint4 v; } u;
    u.s[0] = f2bf(a.x); u.s[1] = f2bf(a.y); u.s[2] = f2bf(a.z); u.s[3] = f2bf(a.w);
    u.s[4] = f2bf(b.x); u.s[5] = f2bf(b.y); u.s[6] = f2bf(b.z); u.s[7] = f2bf(b.w);
    ((uint4*)out)[i] = u.v;
}

// ---------------- weight transpose+convert: w[K][N] fp32 -> wT[N][K] bf16 ----------------
__global__ __launch_bounds__(256)
void transpose_w(const float* __restrict__ w, unsigned short* __restrict__ wT,
                 int K, int N) {
    __shared__ unsigned short Lt[64][65];
    const int k0 = blockIdx.x * 64, n0 = blockIdx.y * 64;
    const int t = threadIdx.x;
    const int r = t >> 4, c4 = (t & 15) * 4;
    #pragma unroll
    for (int i = 0; i < 4; i++) {
        int rr = r + i * 16;
        float4 v = *(const float4*)(w + (k0 + rr) * N + n0 + c4);
        Lt[rr][c4 + 0] = f2bf(v.x); Lt[rr][c4 + 1] = f2bf(v.y);
        Lt[rr][c4 + 2] = f2bf(v.z); Lt[rr][c4 + 3] = f2bf(v.w);
    }
    __syncthreads();
    const int rn = t >> 3, ks = (t & 7) * 8;
    #pragma unroll
    for (int i = 0; i < 2; i++) {
        int rr = rn + i * 32;
        unsigned short tmp[8];
        #pragma unroll
        for (int j = 0; j < 8; j++) tmp[j] = Lt[ks + j][rr];
        *(uint4*)(wT + (n0 + rr) * K + k0 + ks) = *(const uint4*)tmp;
    }
}

// ---------------- QKV GEMM (m97 structure) ----------------
__global__ __launch_bounds__(256)
void qkv_gemm2(const unsigned short* __restrict__ A,
               const unsigned short* __restrict__ Bt,
               const float* __restrict__ bias,
               unsigned short* __restrict__ q_ws,
               unsigned short* __restrict__ k_ws,
               unsigned short* __restrict__ vT_ws)
{
    const int K = 1024;
    __shared__ unsigned short Al[128 * 32];
    __shared__ unsigned short Bl[128 * 32];
    const int tid = threadIdx.x;
    const int lane = tid & 63, w = tid >> 6;
    const int l15 = lane & 15, lhi = lane >> 4;
    const int m0 = blockIdx.x * 128, n0 = blockIdx.y * 128;
    const int wm = (w >> 1) * 64, wn = (w & 1) * 64;

    const int srow = w * 32 + (lane >> 2);
    const int sslot = lane & 3;
    const unsigned short* ga = A + (size_t)(m0 + srow) * K + sslot * 8;
    const unsigned short* gb = Bt + (size_t)(n0 + srow) * K + sslot * 8;
    unsigned short* la = Al + w * 32 * 32;
    unsigned short* lb = Bl + w * 32 * 32;

    f32x4 acc[4][4] = {};

    for (int k0 = 0; k0 < K; k0 += 32) {
        __syncthreads();
        gload_lds16(ga + k0,          la);
        gload_lds16(ga + k0 + 16 * K, la + 16 * 32);
        gload_lds16(gb + k0,          lb);
        gload_lds16(gb + k0 + 16 * K, lb + 16 * 32);
        __syncthreads();
        bf16x8 af[4], bfr[4];
        #pragma unroll
        for (int m = 0; m < 4; m++)
            af[m] = *(const bf16x8*)(Al + (wm + m * 16 + l15) * 32 + lhi * 8);
        #pragma unroll
        for (int n = 0; n < 4; n++)
            bfr[n] = *(const bf16x8*)(Bl + (wn + n * 16 + l15) * 32 + lhi * 8);
        #pragma unroll
        for (int m = 0; m < 4; m++)
            #pragma unroll
            for (int n = 0; n < 4; n++)
                acc[m][n] = __builtin_amdgcn_mfma_f32_16x16x32_bf16(af[m], bfr[n], acc[m][n], 0, 0, 0);
    }

    #pragma unroll
    for (int n = 0; n < 4; n++) {
        int col = n0 + wn + n * 16 + l15;
        float bv = bias[col];
        int which = col >> 10;          // 0=Q 1=K 2=V
        int d = col & 1023;
        int h = d >> 6, hd = d & 63;
        #pragma unroll
        for (int m = 0; m < 4; m++) {
            #pragma unroll
            for (int j = 0; j < 4; j++) {
                int row = m0 + wm + m * 16 + lhi * 4 + j;
                int b = row >> 11, t = row & 2047;
                float val = acc[m][n][j] + bv;
                int bh = b * 16 + h;
                if (which == 0)      q_ws[(bh * 2048 + t) * 64 + hd] = f2bf(val * QSC);
                else if (which == 1) k_ws[(bh * 2048 + t) * 64 + hd] = f2bf(val);
                else                 vT_ws[(bh * 64 + hd) * 2048 + t] = f2bf(val);
            }
        }
    }
}

// ---------------- Flash attention (causal, swapped-QK^T in-register softmax) ----------------
#define QB 128
#define KVB 64
#define LK 72   // LDS row stride: 144B, 16B-aligned

__global__ __launch_bounds__(256)
void attn_fwd(const unsigned short* __restrict__ q_ws,
              const unsigned short* __restrict__ k_ws,
              const unsigned short* __restrict__ vT_ws,
              unsigned short* __restrict__ attn_ws)
{
    __shared__ unsigned short Kl[KVB * LK];     // K tile [k][d]
    __shared__ unsigned short Vl[64 * LK];      // V^T tile [d][k]
    __shared__ unsigned short Pl[4][32 * LK];   // per-wave P [q][k]

    const int bh = blockIdx.x;      // b*16+h
    const int qb = blockIdx.y;
    const int b = bh >> 4, h = bh & 15;
    const int tid = threadIdx.x;
    const int lane = tid & 63, wid = tid >> 6;
    const int l15 = lane & 15, lhi = lane >> 4;
    const int q0 = qb * QB;
    const int qrow = q0 + wid * 32;
    const int tbase = bh * 2048;
    const float NINF = -__builtin_inff();

    bf16x8 qf[2][2];   // Q pre-scaled by QSC in qkv epilogue
    #pragma unroll
    for (int m = 0; m < 2; m++)
        #pragma unroll
        for (int ks = 0; ks < 2; ks++)
            qf[m][ks] = *(const bf16x8*)(q_ws + (tbase + qrow + m * 16 + l15) * 64 + ks * 32 + lhi * 8);

    f32x4 o[2][4] = {};
    float mreg[2] = {NINF, NINF}, lst[2] = {0.f, 0.f};

    const int nkv = (q0 + QB) / KVB;
    for (int kb = 0; kb < nkv; kb++) {
        const int k0 = kb * KVB;
        __syncthreads();
        #pragma unroll
        for (int i = 0; i < 2; i++) {
            int f = i * 256 + tid;
            int row = f >> 3, dq = (f & 7) << 3;
            *(uint4*)(Kl + row * LK + dq) = *(const uint4*)(k_ws + (tbase + k0 + row) * 64 + dq);
            *(uint4*)(Vl + row * LK + dq) = *(const uint4*)(vT_ws + (bh * 64 + row) * 2048 + k0 + dq);
        }
        __syncthreads();
        if (k0 <= qrow + 31) {
            // S^T = K Q^T : col = l15 = q(within m), row = 4*lhi+j = k(within n)
            f32x4 s[2][4] = {};
            #pragma unroll
            for (int ks = 0; ks < 2; ks++) {
                bf16x8 kf[4];
                #pragma unroll
                for (int n = 0; n < 4; n++)
                    kf[n] = *(const bf16x8*)(Kl + (n * 16 + l15) * LK + ks * 32 + lhi * 8);
                #pragma unroll
                for (int m = 0; m < 2; m++)
                    #pragma unroll
                    for (int n = 0; n < 4; n++)
                        s[m][n] = __builtin_amdgcn_mfma_f32_16x16x32_bf16(kf[n], qf[m][ks], s[m][n], 0, 0, 0);
            }
            // causal mask: only the diagonal tile needs it (wave-uniform branch)
            if (k0 + 63 > qrow) {
                #pragma unroll
                for (int m = 0; m < 2; m++) {
                    int qg = qrow + m * 16 + l15;
                    #pragma unroll
                    for (int n = 0; n < 4; n++) {
                        int kg = k0 + n * 16 + lhi * 4;
                        #pragma unroll
                        for (int j = 0; j < 4; j++)
                            s[m][n][j] = (kg + j <= qg) ? s[m][n][j] : NINF;
                    }
                }
            }
            // row max: in-register over 16 vals + 2 shuffles across lhi groups
            float pmax[2];
            #pragma unroll
            for (int m = 0; m < 2; m++) {
                float mx = NINF;
                #pragma unroll
                for (int n = 0; n < 4; n++)
                    #pragma unroll
                    for (int j = 0; j < 4; j++)
                        mx = fmaxf(mx, s[m][n][j]);
                mx = fmaxf(mx, __shfl_xor(mx, 16));
                mx = fmaxf(mx, __shfl_xor(mx, 32));
                pmax[m] = mx;
            }
            bool ok = (pmax[0] <= mreg[0] + 8.f) && (pmax[1] <= mreg[1] + 8.f);
            if (__all(ok)) {
                // defer-max: no rescale, exp against old max (bounded by 2^8)
                #pragma unroll
                for (int m = 0; m < 2; m++) {
                    float rs = 0.f;
                    #pragma unroll
                    for (int n = 0; n < 4; n++)
                        #pragma unroll
                        for (int j = 0; j < 4; j++) {
                            float p = exp2f(s[m][n][j] - mreg[m]);
                            s[m][n][j] = p;
                            rs += p;
                        }
                    rs += __shfl_xor(rs, 16);
                    rs += __shfl_xor(rs, 32);
                    lst[m] += rs;
                }
            } else {
                float al[2];
                #pragma unroll
                for (int m = 0; m < 2; m++) {
                    float mnew = fmaxf(mreg[m], pmax[m]);
                    al[m] = exp2f(mreg[m] - mnew);
                    mreg[m] = mnew;
                    float rs = 0.f;
                    #pragma unroll
                    for (int n = 0; n < 4; n++)
                        #pragma unroll
                        for (int j = 0; j < 4; j++) {
                            float p = exp2f(s[m][n][j] - mnew);
                            s[m][n][j] = p;
                            rs += p;
                        }
                    rs += __shfl_xor(rs, 16);
                    rs += __shfl_xor(rs, 32);
                    lst[m] = lst[m] * al[m] + rs;
                }
                #pragma unroll
                for (int m = 0; m < 2; m++)
                    #pragma unroll
                    for (int j = 0; j < 4; j++) {
                        float a = __shfl(al[m], lhi * 4 + j);
                        #pragma unroll
                        for (int nd = 0; nd < 4; nd++)
                            o[m][nd][j] *= a;
                    }
            }
            // P -> LDS [q][k], packed 8B writes
            #pragma unroll
            for (int m = 0; m < 2; m++)
                #pragma unroll
                for (int n = 0; n < 4; n++) {
                    ushort4 pk;
                    pk.x = bfc(s[m][n][0]); pk.y = bfc(s[m][n][1]);
                    pk.z = bfc(s[m][n][2]); pk.w = bfc(s[m][n][3]);
                    *(ushort4*)(&Pl[wid][(m * 16 + l15) * LK + n * 16 + lhi * 4]) = pk;
                }
            // O += P @ V
            #pragma unroll
            for (int ks = 0; ks < 2; ks++) {
                bf16x8 pf[2], vf[4];
                #pragma unroll
                for (int m = 0; m < 2; m++)
                    pf[m] = *(const bf16x8*)(&Pl[wid][(m * 16 + l15) * LK + ks * 32 + lhi * 8]);
                #pragma unroll
                for (int nd = 0; nd < 4; nd++)
                    vf[nd] = *(const bf16x8*)(Vl + (nd * 16 + l15) * LK + ks * 32 + lhi * 8);
                #pragma unroll
                for (int m = 0; m < 2; m++)
                    #pragma unroll
                    for (int nd = 0; nd < 4; nd++)
                        o[m][nd] = __builtin_amdgcn_mfma_f32_16x16x32_bf16(pf[m], vf[nd], o[m][nd], 0, 0, 0);
            }
        }
    }
    // epilogue: broadcast 1/l from softmax layout (q=l15) to output layout (q=4*lhi+j)
    #pragma unroll
    for (int m = 0; m < 2; m++) {
        #pragma unroll
        for (int j = 0; j < 4; j++) {
            float lv = __shfl(lst[m], lhi * 4 + j);
            float inv = 1.0f / lv;
            int t = qrow + m * 16 + lhi * 4 + j;
            #pragma unroll
            for (int nd = 0; nd < 4; nd++) {
                int d = nd * 16 + l15;
                attn_ws[((b * 2048 + t) * 16 + h) * 64 + d] = f2bf(o[m][nd][j] * inv);
            }
        }
    }
}

// ---------------- Output projection GEMM (m97 structure) ----------------
__global__ __launch_bounds__(256)
void proj_gemm2(const unsigned short* __restrict__ A,
                const unsigned short* __restrict__ Bt,
                const float* __restrict__ bias, float* __restrict__ out)
{
    const int K = 1024, N = 1024;
    __shared__ unsigned short Al[128 * 32];
    __shared__ unsigned short Bl[128 * 32];
    const int tid = threadIdx.x;
    const int lane = tid & 63, w = tid >> 6;
    const int l15 = lane & 15, lhi = lane >> 4;
    const int m0 = blockIdx.x * 128, n0 = blockIdx.y * 128;
    const int wm = (w >> 1) * 64, wn = (w & 1) * 64;

    const int srow = w * 32 + (lane >> 2);
    const int sslot = lane & 3;
    const unsigned short* ga = A + (size_t)(m0 + srow) * K + sslot * 8;
    const unsigned short* gb = Bt + (size_t)(n0 + srow) * K + sslot * 8;
    unsigned short* la = Al + w * 32 * 32;
    unsigned short* lb = Bl + w * 32 * 32;

    f32x4 acc[4][4] = {};

    for (int k0 = 0; k0 < K; k0 += 32) {
        __syncthreads();
        gload_lds16(ga + k0,          la);
        gload_lds16(ga + k0 + 16 * K, la + 16 * 32);
        gload_lds16(gb + k0,          lb);
        gload_lds16(gb + k0 + 16 * K, lb + 16 * 32);
        __syncthreads();
        bf16x8 af[4], bfr[4];
        #pragma unroll
        for (int m = 0; m < 4; m++)
            af[m] = *(const bf16x8*)(Al + (wm + m * 16 + l15) * 32 + lhi * 8);
        #pragma unroll
        for (int n = 0; n < 4; n++)
            bfr[n] = *(const bf16x8*)(Bl + (wn + n * 16 + l15) * 32 + lhi * 8);
        #pragma unroll
        for (int m = 0; m < 4; m++)
            #pragma unroll
            for (int n = 0; n < 4; n++)
                acc[m][n] = __builtin_amdgcn_mfma_f32_16x16x32_bf16(af[m], bfr[n], acc[m][n], 0, 0, 0);
    }

    #pragma unroll
    for (int n = 0; n < 4; n++) {
        int col = n0 + wn + n * 16 + l15;
        float bv = bias[col];
        #pragma unroll
        for (int m = 0; m < 4; m++)
            #pragma unroll
            for (int j = 0; j < 4; j++) {
                int row = m0 + wm + m * 16 + lhi * 4 + j;
                out[row * N + col] = acc[m][n][j] + bv;
            }
    }
}

extern "C" void kernel_launch(void* const* d_in, const int* in_sizes, int n_in,
                              void* d_out, int out_size, void* d_ws, size_t ws_size,
                              hipStream_t stream)
{
    const float* x      = (const float*)d_in[0];
    const float* w_qkv  = (const float*)d_in[1];
    const float* b_qkv  = (const float*)d_in[2];
    const float* w_proj = (const float*)d_in[3];
    const float* b_proj = (const float*)d_in[4];
    float* out = (float*)d_out;

    const size_t SEG = (size_t)8 * 1024 * 1024;
    unsigned short* q_ws    = (unsigned short*)d_ws;
    unsigned short* k_ws    = q_ws + SEG;
    unsigned short* vT_ws   = k_ws + SEG;
    unsigned short* attn_ws = vT_ws + SEG;

    unsigned short* x_bf   = (unsigned short*)d_out;          // d_out as scratch
    unsigned short* wqkvT  = x_bf + SEG;
    unsigned short* wprojT = q_ws;                            // dead after attn

    cvt_bf16<<<4096, 256, 0, stream>>>(x, x_bf);
    transpose_w<<<dim3(16, 48), 256, 0, stream>>>(w_qkv, wqkvT, 1024, 3072);
    qkv_gemm2<<<dim3(64, 24), 256, 0, stream>>>(x_bf, wqkvT, b_qkv, q_ws, k_ws, vT_ws);
    attn_fwd<<<dim3(64, 16), 256, 0, stream>>>(q_ws, k_ws, vT_ws, attn_ws);
    transpose_w<<<dim3(16, 16), 256, 0, stream>>>(w_proj, wprojT, 1024, 1024);
    proj_gemm2<<<dim3(64, 8), 256, 0, stream>>>(attn_ws, wprojT, b_proj, out);
}

// Round 4
// 252.506 us; speedup vs baseline: 2.1304x; 1.0041x over previous
//
#include <hip/hip_runtime.h>

typedef float f32x4 __attribute__((ext_vector_type(4)));
typedef __bf16 bf16x8 __attribute__((ext_vector_type(8)));

static __device__ __forceinline__ unsigned short f2bf(float f) {
    unsigned int u = __builtin_bit_cast(unsigned int, f);
    u += 0x7fffu + ((u >> 16) & 1u);
    return (unsigned short)(u >> 16);
}
static __device__ __forceinline__ unsigned short bfc(float f) {
    return __builtin_bit_cast(unsigned short, (__bf16)f);
}

#define QSC 0.18033688011112042f   // log2(e)/sqrt(HD) folded into Q

typedef const __attribute__((address_space(1))) unsigned int gu32;
typedef __attribute__((address_space(3))) unsigned int lu32;
static __device__ __forceinline__ void gload_lds16(const unsigned short* g, unsigned short* l) {
    __builtin_amdgcn_global_load_lds((gu32*)g, (lu32*)l, 16, 0, 0);
}

// ---------------- fp32 -> bf16 elementwise convert ----------------
__global__ __launch_bounds__(256)
void cvt_bf16(const float* __restrict__ in, unsigned short* __restrict__ out) {
    int i = blockIdx.x * 256 + threadIdx.x;
    const float4* p = (const float4*)in + (size_t)i * 2;
    float4 a = p[0], b = p[1];
    union { unsigned short s[8]; uint4 v; } u;
    u.s[0] = f2bf(a.x); u.s[1] = f2bf(a.y); u.s[2] = f2bf(a.z); u.s[3] = f2bf(a.w);
    u.s[4] = f2bf(b.x); u.s[5] = f2bf(b.y); u.s[6] = f2bf(b.z); u.s[7] = f2bf(b.w);
    ((uint4*)out)[i] = u.v;
}

// ---------------- weight transpose+convert: w[K][N] fp32 -> wT[N][K] bf16 ----------------
__global__ __launch_bounds__(256)
void transpose_w(const float* __restrict__ w, unsigned short* __restrict__ wT,
                 int K, int N) {
    __shared__ unsigned short Lt[64][65];
    const int k0 = blockIdx.x * 64, n0 = blockIdx.y * 64;
    const int t = threadIdx.x;
    const int r = t >> 4, c4 = (t & 15) * 4;
    #pragma unroll
    for (int i = 0; i < 4; i++) {
        int rr = r + i * 16;
        float4 v = *(const float4*)(w + (k0 + rr) * N + n0 + c4);
        Lt[rr][c4 + 0] = f2bf(v.x); Lt[rr][c4 + 1] = f2bf(v.y);
        Lt[rr][c4 + 2] = f2bf(v.z); Lt[rr][c4 + 3] = f2bf(v.w);
    }
    __syncthreads();
    const int rn = t >> 3, ks = (t & 7) * 8;
    #pragma unroll
    for (int i = 0; i < 2; i++) {
        int rr = rn + i * 32;
        unsigned short tmp[8];
        #pragma unroll
        for (int j = 0; j < 8; j++) tmp[j] = Lt[ks + j][rr];
        *(uint4*)(wT + (n0 + rr) * K + k0 + ks) = *(const uint4*)tmp;
    }
}

// ---------------- QKV GEMM (m97 structure) ----------------
__global__ __launch_bounds__(256)
void qkv_gemm2(const unsigned short* __restrict__ A,
               const unsigned short* __restrict__ Bt,
               const float* __restrict__ bias,
               unsigned short* __restrict__ q_ws,
               unsigned short* __restrict__ k_ws,
               unsigned short* __restrict__ vT_ws)
{
    const int K = 1024;
    __shared__ unsigned short Al[128 * 32];
    __shared__ unsigned short Bl[128 * 32];
    const int tid = threadIdx.x;
    const int lane = tid & 63, w = tid >> 6;
    const int l15 = lane & 15, lhi = lane >> 4;
    const int m0 = blockIdx.x * 128, n0 = blockIdx.y * 128;
    const int wm = (w >> 1) * 64, wn = (w & 1) * 64;

    const int srow = w * 32 + (lane >> 2);
    const int sslot = lane & 3;
    const unsigned short* ga = A + (size_t)(m0 + srow) * K + sslot * 8;
    const unsigned short* gb = Bt + (size_t)(n0 + srow) * K + sslot * 8;
    unsigned short* la = Al + w * 32 * 32;
    unsigned short* lb = Bl + w * 32 * 32;

    f32x4 acc[4][4] = {};

    for (int k0 = 0; k0 < K; k0 += 32) {
        __syncthreads();
        gload_lds16(ga + k0,          la);
        gload_lds16(ga + k0 + 16 * K, la + 16 * 32);
        gload_lds16(gb + k0,          lb);
        gload_lds16(gb + k0 + 16 * K, lb + 16 * 32);
        __syncthreads();
        bf16x8 af[4], bfr[4];
        #pragma unroll
        for (int m = 0; m < 4; m++)
            af[m] = *(const bf16x8*)(Al + (wm + m * 16 + l15) * 32 + lhi * 8);
        #pragma unroll
        for (int n = 0; n < 4; n++)
            bfr[n] = *(const bf16x8*)(Bl + (wn + n * 16 + l15) * 32 + lhi * 8);
        #pragma unroll
        for (int m = 0; m < 4; m++)
            #pragma unroll
            for (int n = 0; n < 4; n++)
                acc[m][n] = __builtin_amdgcn_mfma_f32_16x16x32_bf16(af[m], bfr[n], acc[m][n], 0, 0, 0);
    }

    #pragma unroll
    for (int n = 0; n < 4; n++) {
        int col = n0 + wn + n * 16 + l15;
        float bv = bias[col];
        int which = col >> 10;          // 0=Q 1=K 2=V
        int d = col & 1023;
        int h = d >> 6, hd = d & 63;
        #pragma unroll
        for (int m = 0; m < 4; m++) {
            #pragma unroll
            for (int j = 0; j < 4; j++) {
                int row = m0 + wm + m * 16 + lhi * 4 + j;
                int b = row >> 11, t = row & 2047;
                float val = acc[m][n][j] + bv;
                int bh = b * 16 + h;
                if (which == 0)      q_ws[(bh * 2048 + t) * 64 + hd] = f2bf(val * QSC);
                else if (which == 1) k_ws[(bh * 2048 + t) * 64 + hd] = f2bf(val);
                else                 vT_ws[(bh * 64 + hd) * 2048 + t] = f2bf(val);
            }
        }
    }
}

// ---------------- Flash attention (causal) ----------------
// paired q-blocks {15-p, p}: every workgroup does exactly 34 kv-tile iterations.
// K/V double-buffered in LDS, reg-staged with async split, ONE barrier per tile.
#define LKK 72   // LDS row stride: 144B

__global__ __launch_bounds__(256)
void attn_fwd(const unsigned short* __restrict__ q_ws,
              const unsigned short* __restrict__ k_ws,
              const unsigned short* __restrict__ vT_ws,
              unsigned short* __restrict__ attn_ws)
{
    __shared__ unsigned short Kb[2][64 * LKK];
    __shared__ unsigned short Vb[2][64 * LKK];
    __shared__ unsigned short Pl[4][32 * LKK];

    const int bh = blockIdx.x;      // b*16+h
    const int p  = blockIdx.y;      // 0..7 -> handles qb {15-p, p}
    const int b = bh >> 4, h = bh & 15;
    const int tid = threadIdx.x;
    const int lane = tid & 63, wid = tid >> 6;
    const int l15 = lane & 15, lhi = lane >> 4;
    const int tbase = bh * 2048;
    const float NINF = -__builtin_inff();

    const int r0 = tid >> 3;            // staging row 0..31
    const int c0 = (tid & 7) * 8;       // staging elem col (16B chunks)
    const unsigned short* kg = k_ws + (size_t)(tbase + r0) * 64 + c0;
    const unsigned short* vg = vT_ws + ((size_t)bh * 64 + r0) * 2048 + c0;

    #pragma unroll 1
    for (int seg = 0; seg < 2; ++seg) {
        const int qb = seg ? p : 15 - p;
        const int q0 = qb * 128;
        const int qrow = q0 + wid * 32;
        const int nkv = 2 * (qb + 1);

        bf16x8 qf[2][2];   // Q pre-scaled by QSC
        #pragma unroll
        for (int m = 0; m < 2; m++)
            #pragma unroll
            for (int ks = 0; ks < 2; ks++)
                qf[m][ks] = *(const bf16x8*)(q_ws + (size_t)(tbase + qrow + m * 16 + l15) * 64 + ks * 32 + lhi * 8);

        f32x4 o[2][4] = {};
        float mreg[2] = {NINF, NINF}, lst[2] = {0.f, 0.f};

        // prologue: stage tile 0 into buffer 0
        {
            uint4 ka = *(const uint4*)(kg);
            uint4 kb2 = *(const uint4*)(kg + 32 * 64);
            uint4 va = *(const uint4*)(vg);
            uint4 vb2 = *(const uint4*)(vg + 32 * 2048);
            *(uint4*)(&Kb[0][r0 * LKK + c0]) = ka;
            *(uint4*)(&Kb[0][(r0 + 32) * LKK + c0]) = kb2;
            *(uint4*)(&Vb[0][r0 * LKK + c0]) = va;
            *(uint4*)(&Vb[0][(r0 + 32) * LKK + c0]) = vb2;
        }
        __syncthreads();

        int cur = 0;
        for (int kb = 0; kb < nkv; ++kb) {
            const int k0 = kb * 64;
            // prefetch next tile into registers (clamped on last iter; dead write)
            const int knx = (kb + 1 < nkv ? kb + 1 : kb) * 64;
            uint4 ka = *(const uint4*)(kg + (size_t)knx * 64);
            uint4 kb2 = *(const uint4*)(kg + (size_t)(knx + 32) * 64);
            uint4 va = *(const uint4*)(vg + knx);
            uint4 vb2 = *(const uint4*)(vg + 32 * 2048 + knx);

            if (k0 <= qrow + 31) {
                // S^T = K Q^T : q = l15 (within m), k = 4*lhi+j (within n)
                f32x4 s[2][4] = {};
                __builtin_amdgcn_s_setprio(1);
                #pragma unroll
                for (int ks = 0; ks < 2; ks++) {
                    bf16x8 kf[4];
                    #pragma unroll
                    for (int n = 0; n < 4; n++)
                        kf[n] = *(const bf16x8*)(&Kb[cur][(n * 16 + l15) * LKK + ks * 32 + lhi * 8]);
                    #pragma unroll
                    for (int m = 0; m < 2; m++)
                        #pragma unroll
                        for (int n = 0; n < 4; n++)
                            s[m][n] = __builtin_amdgcn_mfma_f32_16x16x32_bf16(kf[n], qf[m][ks], s[m][n], 0, 0, 0);
                }
                __builtin_amdgcn_s_setprio(0);
                // causal mask: only the diagonal tile (wave-uniform branch)
                if (k0 + 63 > qrow) {
                    #pragma unroll
                    for (int m = 0; m < 2; m++) {
                        int qg = qrow + m * 16 + l15;
                        #pragma unroll
                        for (int n = 0; n < 4; n++) {
                            int kgl = k0 + n * 16 + lhi * 4;
                            #pragma unroll
                            for (int j = 0; j < 4; j++)
                                s[m][n][j] = (kgl + j <= qg) ? s[m][n][j] : NINF;
                        }
                    }
                }
                float pmax[2];
                #pragma unroll
                for (int m = 0; m < 2; m++) {
                    float mx = NINF;
                    #pragma unroll
                    for (int n = 0; n < 4; n++)
                        #pragma unroll
                        for (int j = 0; j < 4; j++)
                            mx = fmaxf(mx, s[m][n][j]);
                    mx = fmaxf(mx, __shfl_xor(mx, 16));
                    mx = fmaxf(mx, __shfl_xor(mx, 32));
                    pmax[m] = mx;
                }
                bool ok = (pmax[0] <= mreg[0] + 8.f) && (pmax[1] <= mreg[1] + 8.f);
                if (__all(ok)) {
                    #pragma unroll
                    for (int m = 0; m < 2; m++) {
                        float rs = 0.f;
                        #pragma unroll
                        for (int n = 0; n < 4; n++)
                            #pragma unroll
                            for (int j = 0; j < 4; j++) {
                                float pv = exp2f(s[m][n][j] - mreg[m]);
                                s[m][n][j] = pv;
                                rs += pv;
                            }
                        rs += __shfl_xor(rs, 16);
                        rs += __shfl_xor(rs, 32);
                        lst[m] += rs;
                    }
                } else {
                    float al[2];
                    #pragma unroll
                    for (int m = 0; m < 2; m++) {
                        float mnew = fmaxf(mreg[m], pmax[m]);
                        al[m] = exp2f(mreg[m] - mnew);
                        mreg[m] = mnew;
                        float rs = 0.f;
                        #pragma unroll
                        for (int n = 0; n < 4; n++)
                            #pragma unroll
                            for (int j = 0; j < 4; j++) {
                                float pv = exp2f(s[m][n][j] - mnew);
                                s[m][n][j] = pv;
                                rs += pv;
                            }
                        rs += __shfl_xor(rs, 16);
                        rs += __shfl_xor(rs, 32);
                        lst[m] = lst[m] * al[m] + rs;
                    }
                    #pragma unroll
                    for (int m = 0; m < 2; m++)
                        #pragma unroll
                        for (int j = 0; j < 4; j++) {
                            float a = __shfl(al[m], lhi * 4 + j);
                            #pragma unroll
                            for (int nd = 0; nd < 4; nd++)
                                o[m][nd][j] *= a;
                        }
                }
                // P -> LDS [q][k], packed 8B writes
                #pragma unroll
                for (int m = 0; m < 2; m++)
                    #pragma unroll
                    for (int n = 0; n < 4; n++) {
                        ushort4 pk;
                        pk.x = bfc(s[m][n][0]); pk.y = bfc(s[m][n][1]);
                        pk.z = bfc(s[m][n][2]); pk.w = bfc(s[m][n][3]);
                        *(ushort4*)(&Pl[wid][(m * 16 + l15) * LKK + n * 16 + lhi * 4]) = pk;
                    }
                // O += P @ V
                __builtin_amdgcn_s_setprio(1);
                #pragma unroll
                for (int ks = 0; ks < 2; ks++) {
                    bf16x8 pf[2], vf[4];
                    #pragma unroll
                    for (int m = 0; m < 2; m++)
                        pf[m] = *(const bf16x8*)(&Pl[wid][(m * 16 + l15) * LKK + ks * 32 + lhi * 8]);
                    #pragma unroll
                    for (int nd = 0; nd < 4; nd++)
                        vf[nd] = *(const bf16x8*)(&Vb[cur][(nd * 16 + l15) * LKK + ks * 32 + lhi * 8]);
                    #pragma unroll
                    for (int m = 0; m < 2; m++)
                        #pragma unroll
                        for (int nd = 0; nd < 4; nd++)
                            o[m][nd] = __builtin_amdgcn_mfma_f32_16x16x32_bf16(pf[m], vf[nd], o[m][nd], 0, 0, 0);
                }
                __builtin_amdgcn_s_setprio(0);
            }
            // write prefetched tile into the other buffer (safe: nobody reads it this iter)
            {
                unsigned short* kd = &Kb[cur ^ 1][0];
                unsigned short* vd = &Vb[cur ^ 1][0];
                *(uint4*)(kd + r0 * LKK + c0) = ka;
                *(uint4*)(kd + (r0 + 32) * LKK + c0) = kb2;
                *(uint4*)(vd + r0 * LKK + c0) = va;
                *(uint4*)(vd + (r0 + 32) * LKK + c0) = vb2;
            }
            __syncthreads();
            cur ^= 1;
        }
        // epilogue: broadcast 1/l from softmax layout (q=l15) to output layout
        #pragma unroll
        for (int m = 0; m < 2; m++) {
            #pragma unroll
            for (int j = 0; j < 4; j++) {
                float lv = __shfl(lst[m], lhi * 4 + j);
                float inv = 1.0f / lv;
                int t = qrow + m * 16 + lhi * 4 + j;
                #pragma unroll
                for (int nd = 0; nd < 4; nd++) {
                    int d = nd * 16 + l15;
                    attn_ws[((size_t)(b * 2048 + t) * 16 + h) * 64 + d] = f2bf(o[m][nd][j] * inv);
                }
            }
        }
    }
}

// ---------------- Output projection GEMM (m97 structure) ----------------
__global__ __launch_bounds__(256)
void proj_gemm2(const unsigned short* __restrict__ A,
                const unsigned short* __restrict__ Bt,
                const float* __restrict__ bias, float* __restrict__ out)
{
    const int K = 1024, N = 1024;
    __shared__ unsigned short Al[128 * 32];
    __shared__ unsigned short Bl[128 * 32];
    const int tid = threadIdx.x;
    const int lane = tid & 63, w = tid >> 6;
    const int l15 = lane & 15, lhi = lane >> 4;
    const int m0 = blockIdx.x * 128, n0 = blockIdx.y * 128;
    const int wm = (w >> 1) * 64, wn = (w & 1) * 64;

    const int srow = w * 32 + (lane >> 2);
    const int sslot = lane & 3;
    const unsigned short* ga = A + (size_t)(m0 + srow) * K + sslot * 8;
    const unsigned short* gb = Bt + (size_t)(n0 + srow) * K + sslot * 8;
    unsigned short* la = Al + w * 32 * 32;
    unsigned short* lb = Bl + w * 32 * 32;

    f32x4 acc[4][4] = {};

    for (int k0 = 0; k0 < K; k0 += 32) {
        __syncthreads();
        gload_lds16(ga + k0,          la);
        gload_lds16(ga + k0 + 16 * K, la + 16 * 32);
        gload_lds16(gb + k0,          lb);
        gload_lds16(gb + k0 + 16 * K, lb + 16 * 32);
        __syncthreads();
        bf16x8 af[4], bfr[4];
        #pragma unroll
        for (int m = 0; m < 4; m++)
            af[m] = *(const bf16x8*)(Al + (wm + m * 16 + l15) * 32 + lhi * 8);
        #pragma unroll
        for (int n = 0; n < 4; n++)
            bfr[n] = *(const bf16x8*)(Bl + (wn + n * 16 + l15) * 32 + lhi * 8);
        #pragma unroll
        for (int m = 0; m < 4; m++)
            #pragma unroll
            for (int n = 0; n < 4; n++)
                acc[m][n] = __builtin_amdgcn_mfma_f32_16x16x32_bf16(af[m], bfr[n], acc[m][n], 0, 0, 0);
    }

    #pragma unroll
    for (int n = 0; n < 4; n++) {
        int col = n0 + wn + n * 16 + l15;
        float bv = bias[col];
        #pragma unroll
        for (int m = 0; m < 4; m++)
            #pragma unroll
            for (int j = 0; j < 4; j++) {
                int row = m0 + wm + m * 16 + lhi * 4 + j;
                out[row * N + col] = acc[m][n][j] + bv;
            }
    }
}

extern "C" void kernel_launch(void* const* d_in, const int* in_sizes, int n_in,
                              void* d_out, int out_size, void* d_ws, size_t ws_size,
                              hipStream_t stream)
{
    const float* x      = (const float*)d_in[0];
    const float* w_qkv  = (const float*)d_in[1];
    const float* b_qkv  = (const float*)d_in[2];
    const float* w_proj = (const float*)d_in[3];
    const float* b_proj = (const float*)d_in[4];
    float* out = (float*)d_out;

    const size_t SEG = (size_t)8 * 1024 * 1024;
    unsigned short* q_ws    = (unsigned short*)d_ws;
    unsigned short* k_ws    = q_ws + SEG;
    unsigned short* vT_ws   = k_ws + SEG;
    unsigned short* attn_ws = vT_ws + SEG;

    unsigned short* x_bf   = (unsigned short*)d_out;          // d_out as scratch
    unsigned short* wqkvT  = x_bf + SEG;
    unsigned short* wprojT = q_ws;                            // dead after attn

    cvt_bf16<<<4096, 256, 0, stream>>>(x, x_bf);
    transpose_w<<<dim3(16, 48), 256, 0, stream>>>(w_qkv, wqkvT, 1024, 3072);
    qkv_gemm2<<<dim3(64, 24), 256, 0, stream>>>(x_bf, wqkvT, b_qkv, q_ws, k_ws, vT_ws);
    attn_fwd<<<dim3(64, 8), 256, 0, stream>>>(q_ws, k_ws, vT_ws, attn_ws);
    transpose_w<<<dim3(16, 16), 256, 0, stream>>>(w_proj, wprojT, 1024, 1024);
    proj_gemm2<<<dim3(64, 8), 256, 0, stream>>>(attn_ws, wprojT, b_proj, out);
}

// Round 5
// 201.353 us; speedup vs baseline: 2.6716x; 1.2540x over previous
//
#include <hip/hip_runtime.h>

typedef float f32x4 __attribute__((ext_vector_type(4)));
typedef __bf16 bf16x8 __attribute__((ext_vector_type(8)));

static __device__ __forceinline__ unsigned short f2bf(float f) {
    unsigned int u = __builtin_bit_cast(unsigned int, f);
    u += 0x7fffu + ((u >> 16) & 1u);
    return (unsigned short)(u >> 16);
}
static __device__ __forceinline__ unsigned short bfc(float f) {
    return __builtin_bit_cast(unsigned short, (__bf16)f);
}

#define QSC 0.18033688011112042f   // log2(e)/sqrt(HD) folded into Q

typedef const __attribute__((address_space(1))) unsigned int gu32;
typedef __attribute__((address_space(3))) unsigned int lu32;
static __device__ __forceinline__ void gload_lds16(const unsigned short* g, unsigned short* l) {
    __builtin_amdgcn_global_load_lds((gu32*)g, (lu32*)l, 16, 0, 0);
}

// ---------------- fp32 -> bf16 elementwise convert ----------------
__global__ __launch_bounds__(256)
void cvt_bf16(const float* __restrict__ in, unsigned short* __restrict__ out) {
    int i = blockIdx.x * 256 + threadIdx.x;
    const float4* p = (const float4*)in + (size_t)i * 2;
    float4 a = p[0], b = p[1];
    union { unsigned short s[8]; uint4 v; } u;
    u.s[0] = f2bf(a.x); u.s[1] = f2bf(a.y); u.s[2] = f2bf(a.z); u.s[3] = f2bf(a.w);
    u.s[4] = f2bf(b.x); u.s[5] = f2bf(b.y); u.s[6] = f2bf(b.z); u.s[7] = f2bf(b.w);
    ((uint4*)out)[i] = u.v;
}

// ---------------- weight transpose+convert: w[K][N] fp32 -> wT[N][K] bf16 ----------------
__global__ __launch_bounds__(256)
void transpose_w(const float* __restrict__ w, unsigned short* __restrict__ wT,
                 int K, int N) {
    __shared__ unsigned short Lt[64][65];
    const int k0 = blockIdx.x * 64, n0 = blockIdx.y * 64;
    const int t = threadIdx.x;
    const int r = t >> 4, c4 = (t & 15) * 4;
    #pragma unroll
    for (int i = 0; i < 4; i++) {
        int rr = r + i * 16;
        float4 v = *(const float4*)(w + (k0 + rr) * N + n0 + c4);
        Lt[rr][c4 + 0] = f2bf(v.x); Lt[rr][c4 + 1] = f2bf(v.y);
        Lt[rr][c4 + 2] = f2bf(v.z); Lt[rr][c4 + 3] = f2bf(v.w);
    }
    __syncthreads();
    const int rn = t >> 3, ks = (t & 7) * 8;
    #pragma unroll
    for (int i = 0; i < 2; i++) {
        int rr = rn + i * 32;
        unsigned short tmp[8];
        #pragma unroll
        for (int j = 0; j < 8; j++) tmp[j] = Lt[ks + j][rr];
        *(uint4*)(wT + (n0 + rr) * K + k0 + ks) = *(const uint4*)tmp;
    }
}

// ---------------- QKV GEMM (m97 structure) ----------------
__global__ __launch_bounds__(256)
void qkv_gemm2(const unsigned short* __restrict__ A,
               const unsigned short* __restrict__ Bt,
               const float* __restrict__ bias,
               unsigned short* __restrict__ q_ws,
               unsigned short* __restrict__ k_ws,
               unsigned short* __restrict__ vT_ws)
{
    const int K = 1024;
    __shared__ unsigned short Al[128 * 32];
    __shared__ unsigned short Bl[128 * 32];
    const int tid = threadIdx.x;
    const int lane = tid & 63, w = tid >> 6;
    const int l15 = lane & 15, lhi = lane >> 4;
    const int m0 = blockIdx.x * 128, n0 = blockIdx.y * 128;
    const int wm = (w >> 1) * 64, wn = (w & 1) * 64;

    const int srow = w * 32 + (lane >> 2);
    const int sslot = lane & 3;
    const unsigned short* ga = A + (size_t)(m0 + srow) * K + sslot * 8;
    const unsigned short* gb = Bt + (size_t)(n0 + srow) * K + sslot * 8;
    unsigned short* la = Al + w * 32 * 32;
    unsigned short* lb = Bl + w * 32 * 32;

    f32x4 acc[4][4] = {};

    for (int k0 = 0; k0 < K; k0 += 32) {
        __syncthreads();
        gload_lds16(ga + k0,          la);
        gload_lds16(ga + k0 + 16 * K, la + 16 * 32);
        gload_lds16(gb + k0,          lb);
        gload_lds16(gb + k0 + 16 * K, lb + 16 * 32);
        __syncthreads();
        bf16x8 af[4], bfr[4];
        #pragma unroll
        for (int m = 0; m < 4; m++)
            af[m] = *(const bf16x8*)(Al + (wm + m * 16 + l15) * 32 + lhi * 8);
        #pragma unroll
        for (int n = 0; n < 4; n++)
            bfr[n] = *(const bf16x8*)(Bl + (wn + n * 16 + l15) * 32 + lhi * 8);
        #pragma unroll
        for (int m = 0; m < 4; m++)
            #pragma unroll
            for (int n = 0; n < 4; n++)
                acc[m][n] = __builtin_amdgcn_mfma_f32_16x16x32_bf16(af[m], bfr[n], acc[m][n], 0, 0, 0);
    }

    #pragma unroll
    for (int n = 0; n < 4; n++) {
        int col = n0 + wn + n * 16 + l15;
        float bv = bias[col];
        int which = col >> 10;          // 0=Q 1=K 2=V
        int d = col & 1023;
        int h = d >> 6, hd = d & 63;
        #pragma unroll
        for (int m = 0; m < 4; m++) {
            #pragma unroll
            for (int j = 0; j < 4; j++) {
                int row = m0 + wm + m * 16 + lhi * 4 + j;
                int b = row >> 11, t = row & 2047;
                float val = acc[m][n][j] + bv;
                int bh = b * 16 + h;
                if (which == 0)      q_ws[(bh * 2048 + t) * 64 + hd] = f2bf(val * QSC);
                else if (which == 1) k_ws[(bh * 2048 + t) * 64 + hd] = f2bf(val);
                else                 vT_ws[(bh * 64 + hd) * 2048 + t] = f2bf(val);
            }
        }
    }
}

// ---------------- Flash attention (causal) ----------------
// 8 waves x 16 q-rows; paired q-blocks {15-p, p} => exactly 34 kv-tiles/block.
// K/V double-buffered (stride-72 LDS), reg-staged prefetch, ONE barrier/tile.
// P buffer: linear [16][64] per wave with 16B-chunk XOR swizzle (conflict-free).
#define LKK 72

__global__ __launch_bounds__(512, 4)
void attn_fwd(const unsigned short* __restrict__ q_ws,
              const unsigned short* __restrict__ k_ws,
              const unsigned short* __restrict__ vT_ws,
              unsigned short* __restrict__ attn_ws)
{
    __shared__ unsigned short Kb[2][64 * LKK];   // 18432 B
    __shared__ unsigned short Vb[2][64 * LKK];   // 18432 B
    __shared__ unsigned short Pl[8][16 * 64];    // 16384 B  (total 53248)

    const int bh = blockIdx.x;      // b*16+h
    const int p  = blockIdx.y;      // 0..7 -> handles qb {15-p, p}
    const int b = bh >> 4, h = bh & 15;
    const int tid = threadIdx.x;
    const int lane = tid & 63, wid = tid >> 6;   // 8 waves
    const int l15 = lane & 15, lhi = lane >> 4;
    const int tbase = bh * 2048;
    const float NINF = -__builtin_inff();

    const int r0 = tid >> 3;            // 0..63 staging row
    const int c0 = (tid & 7) * 8;       // 16B chunk col
    const unsigned short* kg = k_ws + (size_t)(tbase + r0) * 64 + c0;
    const unsigned short* vg = vT_ws + ((size_t)bh * 64 + r0) * 2048 + c0;

    unsigned short* Pw = &Pl[wid][0];
    const int xr = l15 & 7;             // P chunk-swizzle key

    #pragma unroll 1
    for (int seg = 0; seg < 2; ++seg) {
        const int qb = seg ? p : 15 - p;
        const int q0 = qb * 128;
        const int qrow = q0 + wid * 16;
        const int nkv = 2 * (qb + 1);

        bf16x8 qf[2];   // Q pre-scaled by QSC
        #pragma unroll
        for (int ks = 0; ks < 2; ks++)
            qf[ks] = *(const bf16x8*)(q_ws + (size_t)(tbase + qrow + l15) * 64 + ks * 32 + lhi * 8);

        f32x4 o[4] = {};
        float mreg = NINF, lst = 0.f;

        // prologue: stage tile 0 into buffer 0
        {
            uint4 ka = *(const uint4*)(kg);
            uint4 va = *(const uint4*)(vg);
            *(uint4*)(&Kb[0][r0 * LKK + c0]) = ka;
            *(uint4*)(&Vb[0][r0 * LKK + c0]) = va;
        }
        __syncthreads();

        int cur = 0;
        for (int kb = 0; kb < nkv; ++kb) {
            const int k0 = kb * 64;
            // prefetch next tile into registers (clamped last iter; dead write)
            const int knx = (kb + 1 < nkv ? kb + 1 : kb) * 64;
            uint4 ka = *(const uint4*)(kg + (size_t)knx * 64);
            uint4 va = *(const uint4*)(vg + knx);

            if (k0 <= qrow + 15) {      // wave-uniform skip of fully-masked tiles
                // S^T = K Q^T : q = l15, k = 16n + 4*lhi + j
                f32x4 s[4] = {};
                __builtin_amdgcn_s_setprio(1);
                #pragma unroll
                for (int ks = 0; ks < 2; ks++) {
                    bf16x8 kf[4];
                    #pragma unroll
                    for (int n = 0; n < 4; n++)
                        kf[n] = *(const bf16x8*)(&Kb[cur][(n * 16 + l15) * LKK + ks * 32 + lhi * 8]);
                    #pragma unroll
                    for (int n = 0; n < 4; n++)
                        s[n] = __builtin_amdgcn_mfma_f32_16x16x32_bf16(kf[n], qf[ks], s[n], 0, 0, 0);
                }
                __builtin_amdgcn_s_setprio(0);
                // causal mask: only the diagonal tile (wave-uniform branch)
                if (k0 + 63 > qrow) {
                    int qg = qrow + l15;
                    #pragma unroll
                    for (int n = 0; n < 4; n++) {
                        int kgl = k0 + n * 16 + lhi * 4;
                        #pragma unroll
                        for (int j = 0; j < 4; j++)
                            s[n][j] = (kgl + j <= qg) ? s[n][j] : NINF;
                    }
                }
                // row max: 16 in-register + 2 shuffles across lhi groups
                float mx = NINF;
                #pragma unroll
                for (int n = 0; n < 4; n++)
                    #pragma unroll
                    for (int j = 0; j < 4; j++)
                        mx = fmaxf(mx, s[n][j]);
                mx = fmaxf(mx, __shfl_xor(mx, 16));
                mx = fmaxf(mx, __shfl_xor(mx, 32));

                if (__all(mx <= mreg + 8.f)) {
                    // defer-max: no rescale, exp against old max (bounded by 2^8)
                    float rs = 0.f;
                    #pragma unroll
                    for (int n = 0; n < 4; n++)
                        #pragma unroll
                        for (int j = 0; j < 4; j++) {
                            float pv = exp2f(s[n][j] - mreg);
                            s[n][j] = pv;
                            rs += pv;
                        }
                    rs += __shfl_xor(rs, 16);
                    rs += __shfl_xor(rs, 32);
                    lst += rs;
                } else {
                    float mnew = fmaxf(mreg, mx);
                    float al = exp2f(mreg - mnew);
                    mreg = mnew;
                    float rs = 0.f;
                    #pragma unroll
                    for (int n = 0; n < 4; n++)
                        #pragma unroll
                        for (int j = 0; j < 4; j++) {
                            float pv = exp2f(s[n][j] - mnew);
                            s[n][j] = pv;
                            rs += pv;
                        }
                    rs += __shfl_xor(rs, 16);
                    rs += __shfl_xor(rs, 32);
                    lst = lst * al + rs;
                    #pragma unroll
                    for (int j = 0; j < 4; j++) {
                        float a = __shfl(al, lhi * 4 + j);
                        #pragma unroll
                        for (int nd = 0; nd < 4; nd++)
                            o[nd][j] *= a;
                    }
                }
                // P -> LDS [q=l15][k], 16B-chunk XOR swizzle, 8B writes
                #pragma unroll
                for (int n = 0; n < 4; n++) {
                    ushort4 pk;
                    pk.x = bfc(s[n][0]); pk.y = bfc(s[n][1]);
                    pk.z = bfc(s[n][2]); pk.w = bfc(s[n][3]);
                    int chunk = (2 * n + (lhi >> 1)) ^ xr;
                    *(ushort4*)(&Pw[l15 * 64 + chunk * 8 + (lhi & 1) * 4]) = pk;
                }
                // O += P @ V
                __builtin_amdgcn_s_setprio(1);
                #pragma unroll
                for (int ks = 0; ks < 2; ks++) {
                    int chunk = (4 * ks + lhi) ^ xr;
                    bf16x8 pf = *(const bf16x8*)(&Pw[l15 * 64 + chunk * 8]);
                    bf16x8 vf[4];
                    #pragma unroll
                    for (int nd = 0; nd < 4; nd++)
                        vf[nd] = *(const bf16x8*)(&Vb[cur][(nd * 16 + l15) * LKK + ks * 32 + lhi * 8]);
                    #pragma unroll
                    for (int nd = 0; nd < 4; nd++)
                        o[nd] = __builtin_amdgcn_mfma_f32_16x16x32_bf16(pf, vf[nd], o[nd], 0, 0, 0);
                }
                __builtin_amdgcn_s_setprio(0);
            }
            // write prefetched tile into the other buffer
            *(uint4*)(&Kb[cur ^ 1][r0 * LKK + c0]) = ka;
            *(uint4*)(&Vb[cur ^ 1][r0 * LKK + c0]) = va;
            __syncthreads();
            cur ^= 1;
        }
        // epilogue: broadcast 1/l from softmax layout (q=l15) to output layout
        #pragma unroll
        for (int j = 0; j < 4; j++) {
            float lv = __shfl(lst, lhi * 4 + j);
            float inv = 1.0f / lv;
            int t = qrow + lhi * 4 + j;
            #pragma unroll
            for (int nd = 0; nd < 4; nd++) {
                int d = nd * 16 + l15;
                attn_ws[((size_t)(b * 2048 + t) * 16 + h) * 64 + d] = f2bf(o[nd][j] * inv);
            }
        }
    }
}

// ---------------- Output projection GEMM (m97 structure) ----------------
__global__ __launch_bounds__(256)
void proj_gemm2(const unsigned short* __restrict__ A,
                const unsigned short* __restrict__ Bt,
                const float* __restrict__ bias, float* __restrict__ out)
{
    const int K = 1024, N = 1024;
    __shared__ unsigned short Al[128 * 32];
    __shared__ unsigned short Bl[128 * 32];
    const int tid = threadIdx.x;
    const int lane = tid & 63, w = tid >> 6;
    const int l15 = lane & 15, lhi = lane >> 4;
    const int m0 = blockIdx.x * 128, n0 = blockIdx.y * 128;
    const int wm = (w >> 1) * 64, wn = (w & 1) * 64;

    const int srow = w * 32 + (lane >> 2);
    const int sslot = lane & 3;
    const unsigned short* ga = A + (size_t)(m0 + srow) * K + sslot * 8;
    const unsigned short* gb = Bt + (size_t)(n0 + srow) * K + sslot * 8;
    unsigned short* la = Al + w * 32 * 32;
    unsigned short* lb = Bl + w * 32 * 32;

    f32x4 acc[4][4] = {};

    for (int k0 = 0; k0 < K; k0 += 32) {
        __syncthreads();
        gload_lds16(ga + k0,          la);
        gload_lds16(ga + k0 + 16 * K, la + 16 * 32);
        gload_lds16(gb + k0,          lb);
        gload_lds16(gb + k0 + 16 * K, lb + 16 * 32);
        __syncthreads();
        bf16x8 af[4], bfr[4];
        #pragma unroll
        for (int m = 0; m < 4; m++)
            af[m] = *(const bf16x8*)(Al + (wm + m * 16 + l15) * 32 + lhi * 8);
        #pragma unroll
        for (int n = 0; n < 4; n++)
            bfr[n] = *(const bf16x8*)(Bl + (wn + n * 16 + l15) * 32 + lhi * 8);
        #pragma unroll
        for (int m = 0; m < 4; m++)
            #pragma unroll
            for (int n = 0; n < 4; n++)
                acc[m][n] = __builtin_amdgcn_mfma_f32_16x16x32_bf16(af[m], bfr[n], acc[m][n], 0, 0, 0);
    }

    #pragma unroll
    for (int n = 0; n < 4; n++) {
        int col = n0 + wn + n * 16 + l15;
        float bv = bias[col];
        #pragma unroll
        for (int m = 0; m < 4; m++)
            #pragma unroll
            for (int j = 0; j < 4; j++) {
                int row = m0 + wm + m * 16 + lhi * 4 + j;
                out[row * N + col] = acc[m][n][j] + bv;
            }
    }
}

extern "C" void kernel_launch(void* const* d_in, const int* in_sizes, int n_in,
                              void* d_out, int out_size, void* d_ws, size_t ws_size,
                              hipStream_t stream)
{
    const float* x      = (const float*)d_in[0];
    const float* w_qkv  = (const float*)d_in[1];
    const float* b_qkv  = (const float*)d_in[2];
    const float* w_proj = (const float*)d_in[3];
    const float* b_proj = (const float*)d_in[4];
    float* out = (float*)d_out;

    const size_t SEG = (size_t)8 * 1024 * 1024;
    unsigned short* q_ws    = (unsigned short*)d_ws;
    unsigned short* k_ws    = q_ws + SEG;
    unsigned short* vT_ws   = k_ws + SEG;
    unsigned short* attn_ws = vT_ws + SEG;

    unsigned short* x_bf   = (unsigned short*)d_out;          // d_out as scratch
    unsigned short* wqkvT  = x_bf + SEG;
    unsigned short* wprojT = q_ws;                            // dead after attn

    cvt_bf16<<<4096, 256, 0, stream>>>(x, x_bf);
    transpose_w<<<dim3(16, 48), 256, 0, stream>>>(w_qkv, wqkvT, 1024, 3072);
    qkv_gemm2<<<dim3(64, 24), 256, 0, stream>>>(x_bf, wqkvT, b_qkv, q_ws, k_ws, vT_ws);
    attn_fwd<<<dim3(64, 8), 512, 0, stream>>>(q_ws, k_ws, vT_ws, attn_ws);
    transpose_w<<<dim3(16, 16), 256, 0, stream>>>(w_proj, wprojT, 1024, 1024);
    proj_gemm2<<<dim3(64, 8), 256, 0, stream>>>(attn_ws, wprojT, b_proj, out);
}

// Round 6
// 199.529 us; speedup vs baseline: 2.6960x; 1.0091x over previous
//
#include <hip/hip_runtime.h>

typedef float f32x4 __attribute__((ext_vector_type(4)));
typedef __bf16 bf16x8 __attribute__((ext_vector_type(8)));

static __device__ __forceinline__ unsigned short f2bf(float f) {
    unsigned int u = __builtin_bit_cast(unsigned int, f);
    u += 0x7fffu + ((u >> 16) & 1u);
    return (unsigned short)(u >> 16);
}
static __device__ __forceinline__ unsigned short bfc(float f) {
    return __builtin_bit_cast(unsigned short, (__bf16)f);
}

#define QSC 0.18033688011112042f   // log2(e)/sqrt(HD) folded into Q

typedef const __attribute__((address_space(1))) unsigned int gu32;
typedef __attribute__((address_space(3))) unsigned int lu32;
static __device__ __forceinline__ void gload_lds16(const unsigned short* g, unsigned short* l) {
    __builtin_amdgcn_global_load_lds((gu32*)g, (lu32*)l, 16, 0, 0);
}

// ---------------- fp32 -> bf16 elementwise convert ----------------
__global__ __launch_bounds__(256)
void cvt_bf16(const float* __restrict__ in, unsigned short* __restrict__ out) {
    int i = blockIdx.x * 256 + threadIdx.x;
    const float4* p = (const float4*)in + (size_t)i * 2;
    float4 a = p[0], b = p[1];
    union { unsigned short s[8]; uint4 v; } u;
    u.s[0] = f2bf(a.x); u.s[1] = f2bf(a.y); u.s[2] = f2bf(a.z); u.s[3] = f2bf(a.w);
    u.s[4] = f2bf(b.x); u.s[5] = f2bf(b.y); u.s[6] = f2bf(b.z); u.s[7] = f2bf(b.w);
    ((uint4*)out)[i] = u.v;
}

// ---------------- weight transpose+convert: w[K][N] fp32 -> wT[N][K] bf16 ----------------
__global__ __launch_bounds__(256)
void transpose_w(const float* __restrict__ w, unsigned short* __restrict__ wT,
                 int K, int N) {
    __shared__ unsigned short Lt[64][65];
    const int k0 = blockIdx.x * 64, n0 = blockIdx.y * 64;
    const int t = threadIdx.x;
    const int r = t >> 4, c4 = (t & 15) * 4;
    #pragma unroll
    for (int i = 0; i < 4; i++) {
        int rr = r + i * 16;
        float4 v = *(const float4*)(w + (k0 + rr) * N + n0 + c4);
        Lt[rr][c4 + 0] = f2bf(v.x); Lt[rr][c4 + 1] = f2bf(v.y);
        Lt[rr][c4 + 2] = f2bf(v.z); Lt[rr][c4 + 3] = f2bf(v.w);
    }
    __syncthreads();
    const int rn = t >> 3, ks = (t & 7) * 8;
    #pragma unroll
    for (int i = 0; i < 2; i++) {
        int rr = rn + i * 32;
        unsigned short tmp[8];
        #pragma unroll
        for (int j = 0; j < 8; j++) tmp[j] = Lt[ks + j][rr];
        *(uint4*)(wT + (n0 + rr) * K + k0 + ks) = *(const uint4*)tmp;
    }
}

// ---------------- QKV GEMM (2-phase prefetch pipeline) ----------------
__global__ __launch_bounds__(256)
void qkv_gemm2(const unsigned short* __restrict__ A,
               const unsigned short* __restrict__ Bt,
               const float* __restrict__ bias,
               unsigned short* __restrict__ q_ws,
               unsigned short* __restrict__ k_ws,
               unsigned short* __restrict__ vT_ws)
{
    const int K = 1024;
    __shared__ unsigned short Al[2][128 * 32];
    __shared__ unsigned short Bl[2][128 * 32];
    const int tid = threadIdx.x;
    const int lane = tid & 63, w = tid >> 6;
    const int l15 = lane & 15, lhi = lane >> 4;
    const int m0 = blockIdx.x * 128, n0 = blockIdx.y * 128;
    const int wm = (w >> 1) * 64, wn = (w & 1) * 64;

    const int srow = w * 32 + (lane >> 2);
    const int sslot = lane & 3;
    const unsigned short* ga = A + (size_t)(m0 + srow) * K + sslot * 8;
    const unsigned short* gb = Bt + (size_t)(n0 + srow) * K + sslot * 8;
    const int lofs = w * 32 * 32;

    f32x4 acc[4][4] = {};

    // prologue: stage tile 0 into buffer 0
    gload_lds16(ga, &Al[0][lofs]);
    gload_lds16(ga + 16 * K, &Al[0][lofs + 512]);
    gload_lds16(gb, &Bl[0][lofs]);
    gload_lds16(gb + 16 * K, &Bl[0][lofs + 512]);
    __syncthreads();

    int cur = 0;
    for (int k0 = 0; k0 < K; k0 += 32) {
        const int nxt = cur ^ 1;
        if (k0 + 32 < K) {   // issue next-tile loads BEFORE compute (overlap)
            gload_lds16(ga + k0 + 32,          &Al[nxt][lofs]);
            gload_lds16(ga + k0 + 32 + 16 * K, &Al[nxt][lofs + 512]);
            gload_lds16(gb + k0 + 32,          &Bl[nxt][lofs]);
            gload_lds16(gb + k0 + 32 + 16 * K, &Bl[nxt][lofs + 512]);
        }
        bf16x8 af[4], bfr[4];
        #pragma unroll
        for (int m = 0; m < 4; m++)
            af[m] = *(const bf16x8*)(&Al[cur][(wm + m * 16 + l15) * 32 + lhi * 8]);
        #pragma unroll
        for (int n = 0; n < 4; n++)
            bfr[n] = *(const bf16x8*)(&Bl[cur][(wn + n * 16 + l15) * 32 + lhi * 8]);
        __builtin_amdgcn_s_setprio(1);
        #pragma unroll
        for (int m = 0; m < 4; m++)
            #pragma unroll
            for (int n = 0; n < 4; n++)
                acc[m][n] = __builtin_amdgcn_mfma_f32_16x16x32_bf16(af[m], bfr[n], acc[m][n], 0, 0, 0);
        __builtin_amdgcn_s_setprio(0);
        __syncthreads();   // drains next-tile loads (they overlapped compute)
        cur = nxt;
    }

    #pragma unroll
    for (int n = 0; n < 4; n++) {
        int col = n0 + wn + n * 16 + l15;
        float bv = bias[col];
        int which = col >> 10;          // 0=Q 1=K 2=V
        int d = col & 1023;
        int h = d >> 6, hd = d & 63;
        #pragma unroll
        for (int m = 0; m < 4; m++) {
            #pragma unroll
            for (int j = 0; j < 4; j++) {
                int row = m0 + wm + m * 16 + lhi * 4 + j;
                int b = row >> 11, t = row & 2047;
                float val = acc[m][n][j] + bv;
                int bh = b * 16 + h;
                if (which == 0)      q_ws[(bh * 2048 + t) * 64 + hd] = f2bf(val * QSC);
                else if (which == 1) k_ws[(bh * 2048 + t) * 64 + hd] = f2bf(val);
                else                 vT_ws[(bh * 64 + hd) * 2048 + t] = f2bf(val);
            }
        }
    }
}

// ---------------- Flash attention (causal) ----------------
// 8 waves x 16 q-rows; paired q-blocks {15-p, p} => exactly 34 kv-tiles/block.
// K/V double-buffered (stride-72 LDS), reg-staged prefetch, ONE barrier/tile.
// P buffer: linear [16][64] per wave with 16B-chunk XOR swizzle (conflict-free).
#define LKK 72

__global__ __launch_bounds__(512, 4)
void attn_fwd(const unsigned short* __restrict__ q_ws,
              const unsigned short* __restrict__ k_ws,
              const unsigned short* __restrict__ vT_ws,
              unsigned short* __restrict__ attn_ws)
{
    __shared__ unsigned short Kb[2][64 * LKK];   // 18432 B
    __shared__ unsigned short Vb[2][64 * LKK];   // 18432 B
    __shared__ unsigned short Pl[8][16 * 64];    // 16384 B  (total 53248)

    const int bh = blockIdx.x;      // b*16+h
    const int p  = blockIdx.y;      // 0..7 -> handles qb {15-p, p}
    const int b = bh >> 4, h = bh & 15;
    const int tid = threadIdx.x;
    const int lane = tid & 63, wid = tid >> 6;   // 8 waves
    const int l15 = lane & 15, lhi = lane >> 4;
    const int tbase = bh * 2048;
    const float NINF = -__builtin_inff();

    const int r0 = tid >> 3;            // 0..63 staging row
    const int c0 = (tid & 7) * 8;       // 16B chunk col
    const unsigned short* kg = k_ws + (size_t)(tbase + r0) * 64 + c0;
    const unsigned short* vg = vT_ws + ((size_t)bh * 64 + r0) * 2048 + c0;

    unsigned short* Pw = &Pl[wid][0];
    const int xr = l15 & 7;             // P chunk-swizzle key

    #pragma unroll 1
    for (int seg = 0; seg < 2; ++seg) {
        const int qb = seg ? p : 15 - p;
        const int q0 = qb * 128;
        const int qrow = q0 + wid * 16;
        const int nkv = 2 * (qb + 1);

        bf16x8 qf[2];   // Q pre-scaled by QSC
        #pragma unroll
        for (int ks = 0; ks < 2; ks++)
            qf[ks] = *(const bf16x8*)(q_ws + (size_t)(tbase + qrow + l15) * 64 + ks * 32 + lhi * 8);

        f32x4 o[4] = {};
        float mreg = NINF, lst = 0.f;

        // prologue: stage tile 0 into buffer 0
        {
            uint4 ka = *(const uint4*)(kg);
            uint4 va = *(const uint4*)(vg);
            *(uint4*)(&Kb[0][r0 * LKK + c0]) = ka;
            *(uint4*)(&Vb[0][r0 * LKK + c0]) = va;
        }
        __syncthreads();

        int cur = 0;
        for (int kb = 0; kb < nkv; ++kb) {
            const int k0 = kb * 64;
            // prefetch next tile into registers (clamped last iter; dead write)
            const int knx = (kb + 1 < nkv ? kb + 1 : kb) * 64;
            uint4 ka = *(const uint4*)(kg + (size_t)knx * 64);
            uint4 va = *(const uint4*)(vg + knx);

            if (k0 <= qrow + 15) {      // wave-uniform skip of fully-masked tiles
                // S^T = K Q^T : q = l15, k = 16n + 4*lhi + j
                f32x4 s[4] = {};
                __builtin_amdgcn_s_setprio(1);
                #pragma unroll
                for (int ks = 0; ks < 2; ks++) {
                    bf16x8 kf[4];
                    #pragma unroll
                    for (int n = 0; n < 4; n++)
                        kf[n] = *(const bf16x8*)(&Kb[cur][(n * 16 + l15) * LKK + ks * 32 + lhi * 8]);
                    #pragma unroll
                    for (int n = 0; n < 4; n++)
                        s[n] = __builtin_amdgcn_mfma_f32_16x16x32_bf16(kf[n], qf[ks], s[n], 0, 0, 0);
                }
                __builtin_amdgcn_s_setprio(0);
                // causal mask: only the diagonal tile (wave-uniform branch)
                if (k0 + 63 > qrow) {
                    int qg = qrow + l15;
                    #pragma unroll
                    for (int n = 0; n < 4; n++) {
                        int kgl = k0 + n * 16 + lhi * 4;
                        #pragma unroll
                        for (int j = 0; j < 4; j++)
                            s[n][j] = (kgl + j <= qg) ? s[n][j] : NINF;
                    }
                }
                // row max: 16 in-register + 2 shuffles across lhi groups
                float mx = NINF;
                #pragma unroll
                for (int n = 0; n < 4; n++)
                    #pragma unroll
                    for (int j = 0; j < 4; j++)
                        mx = fmaxf(mx, s[n][j]);
                mx = fmaxf(mx, __shfl_xor(mx, 16));
                mx = fmaxf(mx, __shfl_xor(mx, 32));

                if (__all(mx <= mreg + 8.f)) {
                    // defer-max: no rescale, exp against old max (bounded by 2^8)
                    float rs = 0.f;
                    #pragma unroll
                    for (int n = 0; n < 4; n++)
                        #pragma unroll
                        for (int j = 0; j < 4; j++) {
                            float pv = exp2f(s[n][j] - mreg);
                            s[n][j] = pv;
                            rs += pv;
                        }
                    rs += __shfl_xor(rs, 16);
                    rs += __shfl_xor(rs, 32);
                    lst += rs;
                } else {
                    float mnew = fmaxf(mreg, mx);
                    float al = exp2f(mreg - mnew);
                    mreg = mnew;
                    float rs = 0.f;
                    #pragma unroll
                    for (int n = 0; n < 4; n++)
                        #pragma unroll
                        for (int j = 0; j < 4; j++) {
                            float pv = exp2f(s[n][j] - mnew);
                            s[n][j] = pv;
                            rs += pv;
                        }
                    rs += __shfl_xor(rs, 16);
                    rs += __shfl_xor(rs, 32);
                    lst = lst * al + rs;
                    #pragma unroll
                    for (int j = 0; j < 4; j++) {
                        float a = __shfl(al, lhi * 4 + j);
                        #pragma unroll
                        for (int nd = 0; nd < 4; nd++)
                            o[nd][j] *= a;
                    }
                }
                // P -> LDS [q=l15][k], 16B-chunk XOR swizzle, 8B writes
                #pragma unroll
                for (int n = 0; n < 4; n++) {
                    ushort4 pk;
                    pk.x = bfc(s[n][0]); pk.y = bfc(s[n][1]);
                    pk.z = bfc(s[n][2]); pk.w = bfc(s[n][3]);
                    int chunk = (2 * n + (lhi >> 1)) ^ xr;
                    *(ushort4*)(&Pw[l15 * 64 + chunk * 8 + (lhi & 1) * 4]) = pk;
                }
                // O += P @ V
                __builtin_amdgcn_s_setprio(1);
                #pragma unroll
                for (int ks = 0; ks < 2; ks++) {
                    int chunk = (4 * ks + lhi) ^ xr;
                    bf16x8 pf = *(const bf16x8*)(&Pw[l15 * 64 + chunk * 8]);
                    bf16x8 vf[4];
                    #pragma unroll
                    for (int nd = 0; nd < 4; nd++)
                        vf[nd] = *(const bf16x8*)(&Vb[cur][(nd * 16 + l15) * LKK + ks * 32 + lhi * 8]);
                    #pragma unroll
                    for (int nd = 0; nd < 4; nd++)
                        o[nd] = __builtin_amdgcn_mfma_f32_16x16x32_bf16(pf, vf[nd], o[nd], 0, 0, 0);
                }
                __builtin_amdgcn_s_setprio(0);
            }
            // write prefetched tile into the other buffer
            *(uint4*)(&Kb[cur ^ 1][r0 * LKK + c0]) = ka;
            *(uint4*)(&Vb[cur ^ 1][r0 * LKK + c0]) = va;
            __syncthreads();
            cur ^= 1;
        }
        // epilogue: broadcast 1/l from softmax layout (q=l15) to output layout
        #pragma unroll
        for (int j = 0; j < 4; j++) {
            float lv = __shfl(lst, lhi * 4 + j);
            float inv = 1.0f / lv;
            int t = qrow + lhi * 4 + j;
            #pragma unroll
            for (int nd = 0; nd < 4; nd++) {
                int d = nd * 16 + l15;
                attn_ws[((size_t)(b * 2048 + t) * 16 + h) * 64 + d] = f2bf(o[nd][j] * inv);
            }
        }
    }
}

// ---------------- Output projection GEMM (2-phase prefetch pipeline) ----------------
__global__ __launch_bounds__(256)
void proj_gemm2(const unsigned short* __restrict__ A,
                const unsigned short* __restrict__ Bt,
                const float* __restrict__ bias, float* __restrict__ out)
{
    const int K = 1024, N = 1024;
    __shared__ unsigned short Al[2][128 * 32];
    __shared__ unsigned short Bl[2][128 * 32];
    const int tid = threadIdx.x;
    const int lane = tid & 63, w = tid >> 6;
    const int l15 = lane & 15, lhi = lane >> 4;
    const int m0 = blockIdx.x * 128, n0 = blockIdx.y * 128;
    const int wm = (w >> 1) * 64, wn = (w & 1) * 64;

    const int srow = w * 32 + (lane >> 2);
    const int sslot = lane & 3;
    const unsigned short* ga = A + (size_t)(m0 + srow) * K + sslot * 8;
    const unsigned short* gb = Bt + (size_t)(n0 + srow) * K + sslot * 8;
    const int lofs = w * 32 * 32;

    f32x4 acc[4][4] = {};

    gload_lds16(ga, &Al[0][lofs]);
    gload_lds16(ga + 16 * K, &Al[0][lofs + 512]);
    gload_lds16(gb, &Bl[0][lofs]);
    gload_lds16(gb + 16 * K, &Bl[0][lofs + 512]);
    __syncthreads();

    int cur = 0;
    for (int k0 = 0; k0 < K; k0 += 32) {
        const int nxt = cur ^ 1;
        if (k0 + 32 < K) {
            gload_lds16(ga + k0 + 32,          &Al[nxt][lofs]);
            gload_lds16(ga + k0 + 32 + 16 * K, &Al[nxt][lofs + 512]);
            gload_lds16(gb + k0 + 32,          &Bl[nxt][lofs]);
            gload_lds16(gb + k0 + 32 + 16 * K, &Bl[nxt][lofs + 512]);
        }
        bf16x8 af[4], bfr[4];
        #pragma unroll
        for (int m = 0; m < 4; m++)
            af[m] = *(const bf16x8*)(&Al[cur][(wm + m * 16 + l15) * 32 + lhi * 8]);
        #pragma unroll
        for (int n = 0; n < 4; n++)
            bfr[n] = *(const bf16x8*)(&Bl[cur][(wn + n * 16 + l15) * 32 + lhi * 8]);
        __builtin_amdgcn_s_setprio(1);
        #pragma unroll
        for (int m = 0; m < 4; m++)
            #pragma unroll
            for (int n = 0; n < 4; n++)
                acc[m][n] = __builtin_amdgcn_mfma_f32_16x16x32_bf16(af[m], bfr[n], acc[m][n], 0, 0, 0);
        __builtin_amdgcn_s_setprio(0);
        __syncthreads();
        cur = nxt;
    }

    #pragma unroll
    for (int n = 0; n < 4; n++) {
        int col = n0 + wn + n * 16 + l15;
        float bv = bias[col];
        #pragma unroll
        for (int m = 0; m < 4; m++)
            #pragma unroll
            for (int j = 0; j < 4; j++) {
                int row = m0 + wm + m * 16 + lhi * 4 + j;
                out[row * N + col] = acc[m][n][j] + bv;
            }
    }
}

extern "C" void kernel_launch(void* const* d_in, const int* in_sizes, int n_in,
                              void* d_out, int out_size, void* d_ws, size_t ws_size,
                              hipStream_t stream)
{
    const float* x      = (const float*)d_in[0];
    const float* w_qkv  = (const float*)d_in[1];
    const float* b_qkv  = (const float*)d_in[2];
    const float* w_proj = (const float*)d_in[3];
    const float* b_proj = (const float*)d_in[4];
    float* out = (float*)d_out;

    const size_t SEG = (size_t)8 * 1024 * 1024;
    unsigned short* q_ws    = (unsigned short*)d_ws;
    unsigned short* k_ws    = q_ws + SEG;
    unsigned short* vT_ws   = k_ws + SEG;
    unsigned short* attn_ws = vT_ws + SEG;

    unsigned short* x_bf   = (unsigned short*)d_out;          // d_out as scratch
    unsigned short* wqkvT  = x_bf + SEG;
    unsigned short* wprojT = q_ws;                            // dead after attn

    cvt_bf16<<<4096, 256, 0, stream>>>(x, x_bf);
    transpose_w<<<dim3(16, 48), 256, 0, stream>>>(w_qkv, wqkvT, 1024, 3072);
    qkv_gemm2<<<dim3(64, 24), 256, 0, stream>>>(x_bf, wqkvT, b_qkv, q_ws, k_ws, vT_ws);
    attn_fwd<<<dim3(64, 8), 512, 0, stream>>>(q_ws, k_ws, vT_ws, attn_ws);
    transpose_w<<<dim3(16, 16), 256, 0, stream>>>(w_proj, wprojT, 1024, 1024);
    proj_gemm2<<<dim3(64, 8), 256, 0, stream>>>(attn_ws, wprojT, b_proj, out);
}